// Round 4
// baseline (5770.865 us; speedup 1.0000x reference)
//
#include <hip/hip_runtime.h>

#define NN 100000      // N_NODES
#define NE 1000000     // N_EDGES
#define HID 75
#define SP 80          // padded feature stride (fp32 h buffers)
#define OUTF 64
#define BN_EPS 1e-5f

#define SCAN_ELEMS 1024
#define SCAN_NBLK ((NN + SCAN_ELEMS - 1) / SCAN_ELEMS)   // 98

// bf16 helpers
__device__ __forceinline__ ushort f2bf(float f) {
    unsigned u = __float_as_uint(f);
    u += 0x7FFF + ((u >> 16) & 1);          // round-to-nearest-even
    return (ushort)(u >> 16);
}
__device__ __forceinline__ float bf_lo(unsigned u) { return __uint_as_float(u << 16); }
__device__ __forceinline__ float bf_hi(unsigned u) { return __uint_as_float(u & 0xFFFF0000u); }

// ---------------- CSR build ----------------
__global__ void hist_kernel(const int* __restrict__ dst, int* __restrict__ hist, int E) {
    int e = blockIdx.x * blockDim.x + threadIdx.x;
    if (e < E) atomicAdd(&hist[dst[e]], 1);
}

__global__ void dinv_kernel(const int* __restrict__ hist, float* __restrict__ dinv, int n) {
    int i = blockIdx.x * blockDim.x + threadIdx.x;
    if (i < n) dinv[i] = rsqrtf((float)hist[i] + 1.0f);   // +1 self-loop
}

__global__ void scan_pass1(const int* __restrict__ hist, int* __restrict__ bsum) {
    __shared__ int sdata[256];
    int base = blockIdx.x * SCAN_ELEMS;
    int t = threadIdx.x;
    int s = 0;
    #pragma unroll
    for (int k = 0; k < 4; ++k) {
        int i = base + t * 4 + k;
        if (i < NN) s += hist[i];
    }
    sdata[t] = s;
    __syncthreads();
    for (int off = 128; off > 0; off >>= 1) {
        if (t < off) sdata[t] += sdata[t + off];
        __syncthreads();
    }
    if (t == 0) bsum[blockIdx.x] = sdata[0];
}

__global__ void scan_pass2(int* __restrict__ bsum, int* __restrict__ row_ptr, int nblk) {
    if (threadIdx.x == 0) {
        int acc = 0;
        for (int i = 0; i < nblk; ++i) { int v = bsum[i]; bsum[i] = acc; acc += v; }
        row_ptr[NN] = acc;
    }
}

__global__ void scan_pass3(const int* __restrict__ hist, const int* __restrict__ bsum,
                           int* __restrict__ row_ptr) {
    __shared__ int sdata[256];
    int base = blockIdx.x * SCAN_ELEMS;
    int t = threadIdx.x;
    int v[4];
    int s = 0;
    #pragma unroll
    for (int k = 0; k < 4; ++k) {
        int i = base + t * 4 + k;
        v[k] = (i < NN) ? hist[i] : 0;
        s += v[k];
    }
    sdata[t] = s;
    __syncthreads();
    for (int off = 1; off < 256; off <<= 1) {
        int x = (t >= off) ? sdata[t - off] : 0;
        __syncthreads();
        sdata[t] += x;
        __syncthreads();
    }
    int pre = bsum[blockIdx.x] + sdata[t] - s;
    #pragma unroll
    for (int k = 0; k < 4; ++k) {
        int i = base + t * 4 + k;
        if (i < NN) { row_ptr[i] = pre; pre += v[k]; }
    }
}

__global__ void csr_fill(const int* __restrict__ src, const int* __restrict__ dst,
                         const int* __restrict__ row_ptr, int* __restrict__ cnt,
                         int* __restrict__ col, int E) {
    int e = blockIdx.x * blockDim.x + threadIdx.x;
    if (e >= E) return;
    int d = dst[e];
    int slot = row_ptr[d] + atomicAdd(&cnt[d], 1);
    col[slot] = src[e];
}

// ---------------- embedding gather ----------------
__global__ void embed_kernel(const int* __restrict__ x, const float* __restrict__ emb,
                             float* __restrict__ h) {
    int t = blockIdx.x * blockDim.x + threadIdx.x;
    if (t >= NN * SP) return;
    int node = t / SP, f = t % SP;
    h[t] = (f < HID) ? emb[x[node] * HID + f] : 0.0f;
}

// ---------------- GEMM: outb[n] = bf16( dinv[n] * (BNReLU(h[n]) @ W) ) ----------------
// 4 rows per thread: each W float4 read from LDS feeds 4 row-accumulators.
#define ROWSTEP(X, ACC) \
    if (BNRELU) { \
        X.x = fmaxf(fmaf(X.x, a4.x, c4.x), 0.f); X.y = fmaxf(fmaf(X.y, a4.y, c4.y), 0.f); \
        X.z = fmaxf(fmaf(X.z, a4.z, c4.z), 0.f); X.w = fmaxf(fmaf(X.w, a4.w, c4.w), 0.f); } \
    ACC.x = fmaf(X.x, w0.x, ACC.x); ACC.y = fmaf(X.x, w0.y, ACC.y); \
    ACC.z = fmaf(X.x, w0.z, ACC.z); ACC.w = fmaf(X.x, w0.w, ACC.w); \
    ACC.x = fmaf(X.y, w1.x, ACC.x); ACC.y = fmaf(X.y, w1.y, ACC.y); \
    ACC.z = fmaf(X.y, w1.z, ACC.z); ACC.w = fmaf(X.y, w1.w, ACC.w); \
    ACC.x = fmaf(X.z, w2.x, ACC.x); ACC.y = fmaf(X.z, w2.y, ACC.y); \
    ACC.z = fmaf(X.z, w2.z, ACC.z); ACC.w = fmaf(X.z, w2.w, ACC.w); \
    ACC.x = fmaf(X.w, w3.x, ACC.x); ACC.y = fmaf(X.w, w3.y, ACC.y); \
    ACC.z = fmaf(X.w, w3.z, ACC.z); ACC.w = fmaf(X.w, w3.w, ACC.w);

template<int J, bool BNRELU>
__global__ void gemm_kernel(const float* __restrict__ h, const float* __restrict__ W,
                            const float* __restrict__ ab, const float* __restrict__ dinv,
                            ushort* __restrict__ outb) {
    constexpr int CJ = (J + 3) / 4;   // 19 or 16
    constexpr int JP = CJ * 4;        // 76 or 64
    constexpr int NB = 256 / CJ;      // 13 or 16 row-groups
    constexpr int ROWS = NB * 4;      // 52 or 64 rows per block
    constexpr int OS = (J == HID) ? 80 : 64;
    __shared__ __align__(16) float Wlds[76 * JP];
    __shared__ __align__(16) float sA[SP];
    __shared__ __align__(16) float sC[SP];
    int tl = threadIdx.x;
    for (int idx = tl; idx < 76 * JP; idx += 256) {
        int k = idx / JP, j = idx % JP;
        Wlds[idx] = (k < HID && j < J) ? W[k * J + j] : 0.0f;
    }
    if (BNRELU && tl < SP) { sA[tl] = ab[tl]; sC[tl] = ab[SP + tl]; }
    __syncthreads();
    int nn_local = tl / CJ;
    int c = tl % CJ;
    if (nn_local >= NB) return;
    int rbase = blockIdx.x * ROWS + nn_local * 4;
    if (rbase >= NN) return;
    int r1 = min(rbase + 1, NN - 1), r2 = min(rbase + 2, NN - 1), r3 = min(rbase + 3, NN - 1);
    const float* h0 = h + (size_t)rbase * SP;
    const float* h1 = h + (size_t)r1 * SP;
    const float* h2 = h + (size_t)r2 * SP;
    const float* h3 = h + (size_t)r3 * SP;
    float4 acc0 = make_float4(0.f, 0.f, 0.f, 0.f);
    float4 acc1 = make_float4(0.f, 0.f, 0.f, 0.f);
    float4 acc2 = make_float4(0.f, 0.f, 0.f, 0.f);
    float4 acc3 = make_float4(0.f, 0.f, 0.f, 0.f);
    #pragma unroll
    for (int k4 = 0; k4 < 19; ++k4) {
        const float* wr = &Wlds[(k4 * 4) * JP + c * 4];
        float4 w0 = *reinterpret_cast<const float4*>(wr);
        float4 w1 = *reinterpret_cast<const float4*>(wr + JP);
        float4 w2 = *reinterpret_cast<const float4*>(wr + 2 * JP);
        float4 w3 = *reinterpret_cast<const float4*>(wr + 3 * JP);
        float4 a4 = make_float4(0.f, 0.f, 0.f, 0.f), c4 = make_float4(0.f, 0.f, 0.f, 0.f);
        if (BNRELU) {
            a4 = *reinterpret_cast<const float4*>(sA + k4 * 4);
            c4 = *reinterpret_cast<const float4*>(sC + k4 * 4);
        }
        float4 x0 = *reinterpret_cast<const float4*>(h0 + k4 * 4);
        float4 x1 = *reinterpret_cast<const float4*>(h1 + k4 * 4);
        float4 x2 = *reinterpret_cast<const float4*>(h2 + k4 * 4);
        float4 x3 = *reinterpret_cast<const float4*>(h3 + k4 * 4);
        ROWSTEP(x0, acc0)
        ROWSTEP(x1, acc1)
        ROWSTEP(x2, acc2)
        ROWSTEP(x3, acc3)
    }
    float d0 = dinv[rbase];
    ushort4 o;
    ushort* orow = outb + (size_t)rbase * OS;
    o.x = f2bf(acc0.x * d0); o.y = f2bf(acc0.y * d0); o.z = f2bf(acc0.z * d0); o.w = f2bf(acc0.w * d0);
    reinterpret_cast<ushort4*>(orow)[c] = o;
    if (J == HID && c == 0) reinterpret_cast<ushort4*>(orow)[19] = make_ushort4(0, 0, 0, 0);
    if (rbase + 1 < NN) {
        float d = dinv[r1];
        orow = outb + (size_t)r1 * OS;
        o.x = f2bf(acc1.x * d); o.y = f2bf(acc1.y * d); o.z = f2bf(acc1.z * d); o.w = f2bf(acc1.w * d);
        reinterpret_cast<ushort4*>(orow)[c] = o;
        if (J == HID && c == 0) reinterpret_cast<ushort4*>(orow)[19] = make_ushort4(0, 0, 0, 0);
    }
    if (rbase + 2 < NN) {
        float d = dinv[r2];
        orow = outb + (size_t)r2 * OS;
        o.x = f2bf(acc2.x * d); o.y = f2bf(acc2.y * d); o.z = f2bf(acc2.z * d); o.w = f2bf(acc2.w * d);
        reinterpret_cast<ushort4*>(orow)[c] = o;
        if (J == HID && c == 0) reinterpret_cast<ushort4*>(orow)[19] = make_ushort4(0, 0, 0, 0);
    }
    if (rbase + 3 < NN) {
        float d = dinv[r3];
        orow = outb + (size_t)r3 * OS;
        o.x = f2bf(acc3.x * d); o.y = f2bf(acc3.y * d); o.z = f2bf(acc3.z * d); o.w = f2bf(acc3.w * d);
        reinterpret_cast<ushort4*>(orow)[c] = o;
        if (J == HID && c == 0) reinterpret_cast<ushort4*>(orow)[19] = make_ushort4(0, 0, 0, 0);
    }
}

// ---------------- CSR gather (bf16 uint2 loads, 4-deep MLP, no barriers) ----------------
#define ACCUM(W) \
    a0 += bf_lo(W.x); a1 += bf_hi(W.x); a2 += bf_lo(W.y); a3 += bf_hi(W.y);

// 20 lanes per row, 8B per lane. grid*block >= NN*20.
__global__ void gather75(const int* __restrict__ row_ptr, const int* __restrict__ col,
                         const uint2* __restrict__ hWb, const float* __restrict__ dinv,
                         float* __restrict__ agg) {
    int t = blockIdx.x * 256 + threadIdx.x;
    if (t >= NN * 20) return;
    int n = t / 20, c = t % 20;
    int beg = row_ptr[n], end = row_ptr[n + 1];
    uint2 v = hWb[(size_t)n * 20 + c];     // self term (pre-scaled by dinv[src])
    float a0 = bf_lo(v.x), a1 = bf_hi(v.x), a2 = bf_lo(v.y), a3 = bf_hi(v.y);
    int e = beg;
    for (; e + 3 < end; e += 4) {
        int s0 = col[e], s1 = col[e + 1], s2 = col[e + 2], s3 = col[e + 3];
        uint2 w0 = hWb[(size_t)s0 * 20 + c];
        uint2 w1 = hWb[(size_t)s1 * 20 + c];
        uint2 w2 = hWb[(size_t)s2 * 20 + c];
        uint2 w3 = hWb[(size_t)s3 * 20 + c];
        ACCUM(w0) ACCUM(w1) ACCUM(w2) ACCUM(w3)
    }
    for (; e < end; ++e) {
        uint2 w0 = hWb[(size_t)col[e] * 20 + c];
        ACCUM(w0)
    }
    float d = dinv[n];
    reinterpret_cast<float4*>(agg)[(size_t)n * 20 + c] =
        make_float4(a0 * d, a1 * d, a2 * d, a3 * d);
}

// 16 lanes per row, 8B per lane. grid*block == NN*16 exactly. Adds bias.
__global__ void gather64(const int* __restrict__ row_ptr, const int* __restrict__ col,
                         const uint2* __restrict__ hWb, const float* __restrict__ dinv,
                         const float* __restrict__ bias, float* __restrict__ out) {
    int t = blockIdx.x * 256 + threadIdx.x;
    int n = t / 16, c = t % 16;
    int beg = row_ptr[n], end = row_ptr[n + 1];
    uint2 v = hWb[(size_t)n * 16 + c];
    float a0 = bf_lo(v.x), a1 = bf_hi(v.x), a2 = bf_lo(v.y), a3 = bf_hi(v.y);
    int e = beg;
    for (; e + 3 < end; e += 4) {
        int s0 = col[e], s1 = col[e + 1], s2 = col[e + 2], s3 = col[e + 3];
        uint2 w0 = hWb[(size_t)s0 * 16 + c];
        uint2 w1 = hWb[(size_t)s1 * 16 + c];
        uint2 w2 = hWb[(size_t)s2 * 16 + c];
        uint2 w3 = hWb[(size_t)s3 * 16 + c];
        ACCUM(w0) ACCUM(w1) ACCUM(w2) ACCUM(w3)
    }
    for (; e < end; ++e) {
        uint2 w0 = hWb[(size_t)col[e] * 16 + c];
        ACCUM(w0)
    }
    float d = dinv[n];
    float4 b = *reinterpret_cast<const float4*>(bias + c * 4);
    reinterpret_cast<float4*>(out)[(size_t)n * 16 + c] =
        make_float4(fmaf(a0, d, b.x), fmaf(a1, d, b.y), fmaf(a2, d, b.z), fmaf(a3, d, b.w));
}

// ---------------- BN stats: column sum & sumsq ----------------
__global__ void stats_kernel(const float* __restrict__ agg, float* __restrict__ stats) {
    __shared__ float ssum[SP], ssq[SP];
    if (threadIdx.x < SP) { ssum[threadIdx.x] = 0.f; ssq[threadIdx.x] = 0.f; }
    __syncthreads();
    int gtid = blockIdx.x * blockDim.x + threadIdx.x;
    int T = gridDim.x * blockDim.x;          // divisible by 20
    int c = gtid % 20;
    int r = gtid / 20;
    int rstep = T / 20;
    float4 s = make_float4(0.f, 0.f, 0.f, 0.f), q = make_float4(0.f, 0.f, 0.f, 0.f);
    for (; r < NN; r += rstep) {
        float4 v = reinterpret_cast<const float4*>(agg)[r * 20 + c];
        s.x += v.x; s.y += v.y; s.z += v.z; s.w += v.w;
        q.x += v.x * v.x; q.y += v.y * v.y; q.z += v.z * v.z; q.w += v.w * v.w;
    }
    atomicAdd(&ssum[c * 4 + 0], s.x); atomicAdd(&ssum[c * 4 + 1], s.y);
    atomicAdd(&ssum[c * 4 + 2], s.z); atomicAdd(&ssum[c * 4 + 3], s.w);
    atomicAdd(&ssq[c * 4 + 0], q.x); atomicAdd(&ssq[c * 4 + 1], q.y);
    atomicAdd(&ssq[c * 4 + 2], q.z); atomicAdd(&ssq[c * 4 + 3], q.w);
    __syncthreads();
    if (threadIdx.x < SP) {
        atomicAdd(&stats[threadIdx.x], ssum[threadIdx.x]);
        atomicAdd(&stats[SP + threadIdx.x], ssq[threadIdx.x]);
    }
}

__global__ void bn_finalize(const float* __restrict__ stats, const float* __restrict__ gamma,
                            const float* __restrict__ beta, float* __restrict__ ab) {
    int f = threadIdx.x;
    if (f >= SP) return;
    float a = 0.f, cc = 0.f;
    if (f < HID) {
        float mu = stats[f] * (1.0f / NN);
        float var = stats[SP + f] * (1.0f / NN) - mu * mu;
        a = gamma[f] * rsqrtf(var + BN_EPS);
        cc = beta[f] - mu * a;
    }
    ab[f] = a;
    ab[SP + f] = cc;
}

// ---------------- host ----------------
extern "C" void kernel_launch(void* const* d_in, const int* in_sizes, int n_in,
                              void* d_out, int out_size, void* d_ws, size_t ws_size,
                              hipStream_t stream) {
    const int*   x      = (const int*)d_in[0];
    const int*   ei     = (const int*)d_in[1];
    const float* emb    = (const float*)d_in[2];
    const float* Ws     = (const float*)d_in[3];
    const float* gammas = (const float*)d_in[5];
    const float* betas  = (const float*)d_in[6];
    const float* W_mu   = (const float*)d_in[7];
    const float* b_mu   = (const float*)d_in[8];
    const float* W_ls   = (const float*)d_in[9];
    const float* b_ls   = (const float*)d_in[10];
    float* out = (float*)d_out;

    const int E = in_sizes[1] / 2;
    const int* src = ei;
    const int* dst = ei + E;

    char* ws = (char*)d_ws;
    float*  dinv    = (float*) (ws + 0);            // NN floats
    float*  stats   = (float*) (ws + 400000);       // 160 floats
    float*  ab      = (float*) (ws + 400640);       // 160 floats
    int*    hist    = (int*)   (ws + 401408);       // NN ints
    int*    row_ptr = (int*)   (ws + 801408);       // NN+1 ints
    int*    cnt     = (int*)   (ws + 1201536);      // NN ints
    int*    bsum    = (int*)   (ws + 1601536);      // SCAN_NBLK ints
    int*    col     = (int*)   (ws + 1602048);      // NE ints (4 MB)
    float*  hA      = (float*) (ws + 5602048);      // NN*SP fp32 (32 MB)
    ushort* hBb     = (ushort*)(ws + 37602048);     // NN*80 bf16 (16 MB)

    // --- CSR build ---
    hipMemsetAsync(hist, 0, NN * sizeof(int), stream);
    hist_kernel<<<(E + 255) / 256, 256, 0, stream>>>(dst, hist, E);
    dinv_kernel<<<(NN + 255) / 256, 256, 0, stream>>>(hist, dinv, NN);
    scan_pass1<<<SCAN_NBLK, 256, 0, stream>>>(hist, bsum);
    scan_pass2<<<1, 64, 0, stream>>>(bsum, row_ptr, SCAN_NBLK);
    scan_pass3<<<SCAN_NBLK, 256, 0, stream>>>(hist, bsum, row_ptr);
    hipMemsetAsync(cnt, 0, NN * sizeof(int), stream);
    csr_fill<<<(E + 255) / 256, 256, 0, stream>>>(src, dst, row_ptr, cnt, col, E);

    // --- h0 = emb[x] ---
    embed_kernel<<<(NN * SP + 255) / 256, 256, 0, stream>>>(x, emb, hA);

    // --- 4 GCN+BN+ReLU layers ---
    for (int layer = 0; layer < 4; ++layer) {
        const float* W = Ws + (size_t)layer * HID * HID;
        if (layer == 0)
            gemm_kernel<HID, false><<<(NN + 51) / 52, 256, 0, stream>>>(hA, W, ab, dinv, hBb);
        else
            gemm_kernel<HID, true><<<(NN + 51) / 52, 256, 0, stream>>>(hA, W, ab, dinv, hBb);
        gather75<<<(NN * 20 + 255) / 256, 256, 0, stream>>>(row_ptr, col, (const uint2*)hBb, dinv, hA);
        hipMemsetAsync(stats, 0, 2 * SP * sizeof(float), stream);
        stats_kernel<<<640, 256, 0, stream>>>(hA, stats);
        bn_finalize<<<1, 128, 0, stream>>>(stats, gammas + layer * HID, betas + layer * HID, ab);
    }

    // --- mu ---
    gemm_kernel<OUTF, true><<<(NN + 63) / 64, 256, 0, stream>>>(hA, W_mu, ab, dinv, hBb);
    gather64<<<(NN * 16) / 256, 256, 0, stream>>>(row_ptr, col, (const uint2*)hBb, dinv, b_mu, out);

    // --- logstd ---
    float* out2 = out + (size_t)NN * OUTF;
    gemm_kernel<OUTF, true><<<(NN + 63) / 64, 256, 0, stream>>>(hA, W_ls, ab, dinv, hBb);
    gather64<<<(NN * 16) / 256, 256, 0, stream>>>(row_ptr, col, (const uint2*)hBb, dinv, b_ls, out2);
}

// Round 5
// 4171.507 us; speedup vs baseline: 1.3834x; 1.3834x over previous
//
#include <hip/hip_runtime.h>

#define NN 100000      // N_NODES
#define NE 1000000     // N_EDGES
#define HID 75
#define SP 80          // padded feature stride (fp32 h buffers)
#define OUTF 64
#define BN_EPS 1e-5f

#define SCAN_ELEMS 1024
#define SCAN_NBLK ((NN + SCAN_ELEMS - 1) / SCAN_ELEMS)   // 98

// bf16 helpers
__device__ __forceinline__ ushort f2bf(float f) {
    unsigned u = __float_as_uint(f);
    u += 0x7FFF + ((u >> 16) & 1);          // round-to-nearest-even
    return (ushort)(u >> 16);
}
__device__ __forceinline__ float bf_lo(unsigned u) { return __uint_as_float(u << 16); }
__device__ __forceinline__ float bf_hi(unsigned u) { return __uint_as_float(u & 0xFFFF0000u); }

// ---------------- CSR build ----------------
__global__ void hist_kernel(const int* __restrict__ dst, int* __restrict__ hist, int E) {
    int e = blockIdx.x * blockDim.x + threadIdx.x;
    if (e < E) atomicAdd(&hist[dst[e]], 1);
}

__global__ void dinv_kernel(const int* __restrict__ hist, float* __restrict__ dinv, int n) {
    int i = blockIdx.x * blockDim.x + threadIdx.x;
    if (i < n) dinv[i] = rsqrtf((float)hist[i] + 1.0f);   // +1 self-loop
}

__global__ void scan_pass1(const int* __restrict__ hist, int* __restrict__ bsum) {
    __shared__ int sdata[256];
    int base = blockIdx.x * SCAN_ELEMS;
    int t = threadIdx.x;
    int s = 0;
    #pragma unroll
    for (int k = 0; k < 4; ++k) {
        int i = base + t * 4 + k;
        if (i < NN) s += hist[i];
    }
    sdata[t] = s;
    __syncthreads();
    for (int off = 128; off > 0; off >>= 1) {
        if (t < off) sdata[t] += sdata[t + off];
        __syncthreads();
    }
    if (t == 0) bsum[blockIdx.x] = sdata[0];
}

__global__ void scan_pass2(int* __restrict__ bsum, int* __restrict__ row_ptr, int nblk) {
    if (threadIdx.x == 0) {
        int acc = 0;
        for (int i = 0; i < nblk; ++i) { int v = bsum[i]; bsum[i] = acc; acc += v; }
        row_ptr[NN] = acc;
    }
}

__global__ void scan_pass3(const int* __restrict__ hist, const int* __restrict__ bsum,
                           int* __restrict__ row_ptr) {
    __shared__ int sdata[256];
    int base = blockIdx.x * SCAN_ELEMS;
    int t = threadIdx.x;
    int v[4];
    int s = 0;
    #pragma unroll
    for (int k = 0; k < 4; ++k) {
        int i = base + t * 4 + k;
        v[k] = (i < NN) ? hist[i] : 0;
        s += v[k];
    }
    sdata[t] = s;
    __syncthreads();
    for (int off = 1; off < 256; off <<= 1) {
        int x = (t >= off) ? sdata[t - off] : 0;
        __syncthreads();
        sdata[t] += x;
        __syncthreads();
    }
    int pre = bsum[blockIdx.x] + sdata[t] - s;
    #pragma unroll
    for (int k = 0; k < 4; ++k) {
        int i = base + t * 4 + k;
        if (i < NN) { row_ptr[i] = pre; pre += v[k]; }
    }
}

__global__ void csr_fill(const int* __restrict__ src, const int* __restrict__ dst,
                         const int* __restrict__ row_ptr, int* __restrict__ cnt,
                         int* __restrict__ col, int E) {
    int e = blockIdx.x * blockDim.x + threadIdx.x;
    if (e >= E) return;
    int d = dst[e];
    int slot = row_ptr[d] + atomicAdd(&cnt[d], 1);
    col[slot] = src[e];
}

// ---------------- embedding gather ----------------
__global__ void embed_kernel(const int* __restrict__ x, const float* __restrict__ emb,
                             float* __restrict__ h) {
    int t = blockIdx.x * blockDim.x + threadIdx.x;
    if (t >= NN * SP) return;
    int node = t / SP, f = t % SP;
    h[t] = (f < HID) ? emb[x[node] * HID + f] : 0.0f;
}

// ---------------- GEMM: outb[n] = bf16( dinv[n] * (BNReLU(h[n]) @ W) ) ----------------
// 4 rows per thread: each W float4 read from LDS feeds 4 row-accumulators.
// __launch_bounds__(256,2): 8 waves/CU min -> VGPR cap 256, prevents the 64-VGPR
// default cap (1024-thread flat-wg assumption) that caused massive scratch spill.
#define ROWSTEP(X, ACC) \
    if (BNRELU) { \
        X.x = fmaxf(fmaf(X.x, a4.x, c4.x), 0.f); X.y = fmaxf(fmaf(X.y, a4.y, c4.y), 0.f); \
        X.z = fmaxf(fmaf(X.z, a4.z, c4.z), 0.f); X.w = fmaxf(fmaf(X.w, a4.w, c4.w), 0.f); } \
    ACC.x = fmaf(X.x, w0.x, ACC.x); ACC.y = fmaf(X.x, w0.y, ACC.y); \
    ACC.z = fmaf(X.x, w0.z, ACC.z); ACC.w = fmaf(X.x, w0.w, ACC.w); \
    ACC.x = fmaf(X.y, w1.x, ACC.x); ACC.y = fmaf(X.y, w1.y, ACC.y); \
    ACC.z = fmaf(X.y, w1.z, ACC.z); ACC.w = fmaf(X.y, w1.w, ACC.w); \
    ACC.x = fmaf(X.z, w2.x, ACC.x); ACC.y = fmaf(X.z, w2.y, ACC.y); \
    ACC.z = fmaf(X.z, w2.z, ACC.z); ACC.w = fmaf(X.z, w2.w, ACC.w); \
    ACC.x = fmaf(X.w, w3.x, ACC.x); ACC.y = fmaf(X.w, w3.y, ACC.y); \
    ACC.z = fmaf(X.w, w3.z, ACC.z); ACC.w = fmaf(X.w, w3.w, ACC.w);

template<int J, bool BNRELU>
__global__ __launch_bounds__(256, 2)
void gemm_kernel(const float* __restrict__ h, const float* __restrict__ W,
                 const float* __restrict__ ab, const float* __restrict__ dinv,
                 ushort* __restrict__ outb) {
    constexpr int CJ = (J + 3) / 4;   // 19 or 16
    constexpr int JP = CJ * 4;        // 76 or 64
    constexpr int NB = 256 / CJ;      // 13 or 16 row-groups
    constexpr int ROWS = NB * 4;      // 52 or 64 rows per block
    constexpr int OS = (J == HID) ? 80 : 64;
    __shared__ __align__(16) float Wlds[76 * JP];
    __shared__ __align__(16) float sA[SP];
    __shared__ __align__(16) float sC[SP];
    int tl = threadIdx.x;
    for (int idx = tl; idx < 76 * JP; idx += 256) {
        int k = idx / JP, j = idx % JP;
        Wlds[idx] = (k < HID && j < J) ? W[k * J + j] : 0.0f;
    }
    if (BNRELU && tl < SP) { sA[tl] = ab[tl]; sC[tl] = ab[SP + tl]; }
    __syncthreads();
    int nn_local = tl / CJ;
    int c = tl % CJ;
    if (nn_local >= NB) return;
    int rbase = blockIdx.x * ROWS + nn_local * 4;
    if (rbase >= NN) return;
    int r1 = min(rbase + 1, NN - 1), r2 = min(rbase + 2, NN - 1), r3 = min(rbase + 3, NN - 1);
    const float* h0 = h + (size_t)rbase * SP;
    const float* h1 = h + (size_t)r1 * SP;
    const float* h2 = h + (size_t)r2 * SP;
    const float* h3 = h + (size_t)r3 * SP;
    float4 acc0 = make_float4(0.f, 0.f, 0.f, 0.f);
    float4 acc1 = make_float4(0.f, 0.f, 0.f, 0.f);
    float4 acc2 = make_float4(0.f, 0.f, 0.f, 0.f);
    float4 acc3 = make_float4(0.f, 0.f, 0.f, 0.f);
    #pragma unroll
    for (int k4 = 0; k4 < 19; ++k4) {
        const float* wr = &Wlds[(k4 * 4) * JP + c * 4];
        float4 w0 = *reinterpret_cast<const float4*>(wr);
        float4 w1 = *reinterpret_cast<const float4*>(wr + JP);
        float4 w2 = *reinterpret_cast<const float4*>(wr + 2 * JP);
        float4 w3 = *reinterpret_cast<const float4*>(wr + 3 * JP);
        float4 a4 = make_float4(0.f, 0.f, 0.f, 0.f), c4 = make_float4(0.f, 0.f, 0.f, 0.f);
        if (BNRELU) {
            a4 = *reinterpret_cast<const float4*>(sA + k4 * 4);
            c4 = *reinterpret_cast<const float4*>(sC + k4 * 4);
        }
        float4 x0 = *reinterpret_cast<const float4*>(h0 + k4 * 4);
        float4 x1 = *reinterpret_cast<const float4*>(h1 + k4 * 4);
        float4 x2 = *reinterpret_cast<const float4*>(h2 + k4 * 4);
        float4 x3 = *reinterpret_cast<const float4*>(h3 + k4 * 4);
        ROWSTEP(x0, acc0)
        ROWSTEP(x1, acc1)
        ROWSTEP(x2, acc2)
        ROWSTEP(x3, acc3)
    }
    float d0 = dinv[rbase];
    ushort4 o;
    ushort* orow = outb + (size_t)rbase * OS;
    o.x = f2bf(acc0.x * d0); o.y = f2bf(acc0.y * d0); o.z = f2bf(acc0.z * d0); o.w = f2bf(acc0.w * d0);
    reinterpret_cast<ushort4*>(orow)[c] = o;
    if (J == HID && c == 0) reinterpret_cast<ushort4*>(orow)[19] = make_ushort4(0, 0, 0, 0);
    if (rbase + 1 < NN) {
        float d = dinv[r1];
        orow = outb + (size_t)r1 * OS;
        o.x = f2bf(acc1.x * d); o.y = f2bf(acc1.y * d); o.z = f2bf(acc1.z * d); o.w = f2bf(acc1.w * d);
        reinterpret_cast<ushort4*>(orow)[c] = o;
        if (J == HID && c == 0) reinterpret_cast<ushort4*>(orow)[19] = make_ushort4(0, 0, 0, 0);
    }
    if (rbase + 2 < NN) {
        float d = dinv[r2];
        orow = outb + (size_t)r2 * OS;
        o.x = f2bf(acc2.x * d); o.y = f2bf(acc2.y * d); o.z = f2bf(acc2.z * d); o.w = f2bf(acc2.w * d);
        reinterpret_cast<ushort4*>(orow)[c] = o;
        if (J == HID && c == 0) reinterpret_cast<ushort4*>(orow)[19] = make_ushort4(0, 0, 0, 0);
    }
    if (rbase + 3 < NN) {
        float d = dinv[r3];
        orow = outb + (size_t)r3 * OS;
        o.x = f2bf(acc3.x * d); o.y = f2bf(acc3.y * d); o.z = f2bf(acc3.z * d); o.w = f2bf(acc3.w * d);
        reinterpret_cast<ushort4*>(orow)[c] = o;
        if (J == HID && c == 0) reinterpret_cast<ushort4*>(orow)[19] = make_ushort4(0, 0, 0, 0);
    }
}

// ---------------- CSR gather (bf16 uint2 loads, 4-deep MLP, no barriers) ----------------
#define ACCUM(W) \
    a0 += bf_lo(W.x); a1 += bf_hi(W.x); a2 += bf_lo(W.y); a3 += bf_hi(W.y);

// 20 lanes per row, 8B per lane. grid*block >= NN*20.
__global__ void gather75(const int* __restrict__ row_ptr, const int* __restrict__ col,
                         const uint2* __restrict__ hWb, const float* __restrict__ dinv,
                         float* __restrict__ agg) {
    int t = blockIdx.x * 256 + threadIdx.x;
    if (t >= NN * 20) return;
    int n = t / 20, c = t % 20;
    int beg = row_ptr[n], end = row_ptr[n + 1];
    uint2 v = hWb[(size_t)n * 20 + c];     // self term (pre-scaled by dinv[src])
    float a0 = bf_lo(v.x), a1 = bf_hi(v.x), a2 = bf_lo(v.y), a3 = bf_hi(v.y);
    int e = beg;
    for (; e + 3 < end; e += 4) {
        int s0 = col[e], s1 = col[e + 1], s2 = col[e + 2], s3 = col[e + 3];
        uint2 w0 = hWb[(size_t)s0 * 20 + c];
        uint2 w1 = hWb[(size_t)s1 * 20 + c];
        uint2 w2 = hWb[(size_t)s2 * 20 + c];
        uint2 w3 = hWb[(size_t)s3 * 20 + c];
        ACCUM(w0) ACCUM(w1) ACCUM(w2) ACCUM(w3)
    }
    for (; e < end; ++e) {
        uint2 w0 = hWb[(size_t)col[e] * 20 + c];
        ACCUM(w0)
    }
    float d = dinv[n];
    reinterpret_cast<float4*>(agg)[(size_t)n * 20 + c] =
        make_float4(a0 * d, a1 * d, a2 * d, a3 * d);
}

// 16 lanes per row, 8B per lane. grid*block == NN*16 exactly. Adds bias.
__global__ void gather64(const int* __restrict__ row_ptr, const int* __restrict__ col,
                         const uint2* __restrict__ hWb, const float* __restrict__ dinv,
                         const float* __restrict__ bias, float* __restrict__ out) {
    int t = blockIdx.x * 256 + threadIdx.x;
    int n = t / 16, c = t % 16;
    int beg = row_ptr[n], end = row_ptr[n + 1];
    uint2 v = hWb[(size_t)n * 16 + c];
    float a0 = bf_lo(v.x), a1 = bf_hi(v.x), a2 = bf_lo(v.y), a3 = bf_hi(v.y);
    int e = beg;
    for (; e + 3 < end; e += 4) {
        int s0 = col[e], s1 = col[e + 1], s2 = col[e + 2], s3 = col[e + 3];
        uint2 w0 = hWb[(size_t)s0 * 16 + c];
        uint2 w1 = hWb[(size_t)s1 * 16 + c];
        uint2 w2 = hWb[(size_t)s2 * 16 + c];
        uint2 w3 = hWb[(size_t)s3 * 16 + c];
        ACCUM(w0) ACCUM(w1) ACCUM(w2) ACCUM(w3)
    }
    for (; e < end; ++e) {
        uint2 w0 = hWb[(size_t)col[e] * 16 + c];
        ACCUM(w0)
    }
    float d = dinv[n];
    float4 b = *reinterpret_cast<const float4*>(bias + c * 4);
    reinterpret_cast<float4*>(out)[(size_t)n * 16 + c] =
        make_float4(fmaf(a0, d, b.x), fmaf(a1, d, b.y), fmaf(a2, d, b.z), fmaf(a3, d, b.w));
}

// ---------------- BN stats: column sum & sumsq ----------------
__global__ void stats_kernel(const float* __restrict__ agg, float* __restrict__ stats) {
    __shared__ float ssum[SP], ssq[SP];
    if (threadIdx.x < SP) { ssum[threadIdx.x] = 0.f; ssq[threadIdx.x] = 0.f; }
    __syncthreads();
    int gtid = blockIdx.x * blockDim.x + threadIdx.x;
    int T = gridDim.x * blockDim.x;          // divisible by 20
    int c = gtid % 20;
    int r = gtid / 20;
    int rstep = T / 20;
    float4 s = make_float4(0.f, 0.f, 0.f, 0.f), q = make_float4(0.f, 0.f, 0.f, 0.f);
    for (; r < NN; r += rstep) {
        float4 v = reinterpret_cast<const float4*>(agg)[r * 20 + c];
        s.x += v.x; s.y += v.y; s.z += v.z; s.w += v.w;
        q.x += v.x * v.x; q.y += v.y * v.y; q.z += v.z * v.z; q.w += v.w * v.w;
    }
    atomicAdd(&ssum[c * 4 + 0], s.x); atomicAdd(&ssum[c * 4 + 1], s.y);
    atomicAdd(&ssum[c * 4 + 2], s.z); atomicAdd(&ssum[c * 4 + 3], s.w);
    atomicAdd(&ssq[c * 4 + 0], q.x); atomicAdd(&ssq[c * 4 + 1], q.y);
    atomicAdd(&ssq[c * 4 + 2], q.z); atomicAdd(&ssq[c * 4 + 3], q.w);
    __syncthreads();
    if (threadIdx.x < SP) {
        atomicAdd(&stats[threadIdx.x], ssum[threadIdx.x]);
        atomicAdd(&stats[SP + threadIdx.x], ssq[threadIdx.x]);
    }
}

__global__ void bn_finalize(const float* __restrict__ stats, const float* __restrict__ gamma,
                            const float* __restrict__ beta, float* __restrict__ ab) {
    int f = threadIdx.x;
    if (f >= SP) return;
    float a = 0.f, cc = 0.f;
    if (f < HID) {
        float mu = stats[f] * (1.0f / NN);
        float var = stats[SP + f] * (1.0f / NN) - mu * mu;
        a = gamma[f] * rsqrtf(var + BN_EPS);
        cc = beta[f] - mu * a;
    }
    ab[f] = a;
    ab[SP + f] = cc;
}

// ---------------- host ----------------
extern "C" void kernel_launch(void* const* d_in, const int* in_sizes, int n_in,
                              void* d_out, int out_size, void* d_ws, size_t ws_size,
                              hipStream_t stream) {
    const int*   x      = (const int*)d_in[0];
    const int*   ei     = (const int*)d_in[1];
    const float* emb    = (const float*)d_in[2];
    const float* Ws     = (const float*)d_in[3];
    const float* gammas = (const float*)d_in[5];
    const float* betas  = (const float*)d_in[6];
    const float* W_mu   = (const float*)d_in[7];
    const float* b_mu   = (const float*)d_in[8];
    const float* W_ls   = (const float*)d_in[9];
    const float* b_ls   = (const float*)d_in[10];
    float* out = (float*)d_out;

    const int E = in_sizes[1] / 2;
    const int* src = ei;
    const int* dst = ei + E;

    char* ws = (char*)d_ws;
    float*  dinv    = (float*) (ws + 0);            // NN floats
    float*  stats   = (float*) (ws + 400000);       // 160 floats
    float*  ab      = (float*) (ws + 400640);       // 160 floats
    int*    hist    = (int*)   (ws + 401408);       // NN ints
    int*    row_ptr = (int*)   (ws + 801408);       // NN+1 ints
    int*    cnt     = (int*)   (ws + 1201536);      // NN ints
    int*    bsum    = (int*)   (ws + 1601536);      // SCAN_NBLK ints
    int*    col     = (int*)   (ws + 1602048);      // NE ints (4 MB)
    float*  hA      = (float*) (ws + 5602048);      // NN*SP fp32 (32 MB)
    ushort* hBb     = (ushort*)(ws + 37602048);     // NN*80 bf16 (16 MB)

    // --- CSR build ---
    hipMemsetAsync(hist, 0, NN * sizeof(int), stream);
    hist_kernel<<<(E + 255) / 256, 256, 0, stream>>>(dst, hist, E);
    dinv_kernel<<<(NN + 255) / 256, 256, 0, stream>>>(hist, dinv, NN);
    scan_pass1<<<SCAN_NBLK, 256, 0, stream>>>(hist, bsum);
    scan_pass2<<<1, 64, 0, stream>>>(bsum, row_ptr, SCAN_NBLK);
    scan_pass3<<<SCAN_NBLK, 256, 0, stream>>>(hist, bsum, row_ptr);
    hipMemsetAsync(cnt, 0, NN * sizeof(int), stream);
    csr_fill<<<(E + 255) / 256, 256, 0, stream>>>(src, dst, row_ptr, cnt, col, E);

    // --- h0 = emb[x] ---
    embed_kernel<<<(NN * SP + 255) / 256, 256, 0, stream>>>(x, emb, hA);

    // --- 4 GCN+BN+ReLU layers ---
    for (int layer = 0; layer < 4; ++layer) {
        const float* W = Ws + (size_t)layer * HID * HID;
        if (layer == 0)
            gemm_kernel<HID, false><<<(NN + 51) / 52, 256, 0, stream>>>(hA, W, ab, dinv, hBb);
        else
            gemm_kernel<HID, true><<<(NN + 51) / 52, 256, 0, stream>>>(hA, W, ab, dinv, hBb);
        gather75<<<(NN * 20 + 255) / 256, 256, 0, stream>>>(row_ptr, col, (const uint2*)hBb, dinv, hA);
        hipMemsetAsync(stats, 0, 2 * SP * sizeof(float), stream);
        stats_kernel<<<640, 256, 0, stream>>>(hA, stats);
        bn_finalize<<<1, 128, 0, stream>>>(stats, gammas + layer * HID, betas + layer * HID, ab);
    }

    // --- mu ---
    gemm_kernel<OUTF, true><<<(NN + 63) / 64, 256, 0, stream>>>(hA, W_mu, ab, dinv, hBb);
    gather64<<<(NN * 16) / 256, 256, 0, stream>>>(row_ptr, col, (const uint2*)hBb, dinv, b_mu, out);

    // --- logstd ---
    float* out2 = out + (size_t)NN * OUTF;
    gemm_kernel<OUTF, true><<<(NN + 63) / 64, 256, 0, stream>>>(hA, W_ls, ab, dinv, hBb);
    gather64<<<(NN * 16) / 256, 256, 0, stream>>>(row_ptr, col, (const uint2*)hBb, dinv, b_ls, out2);
}

// Round 6
// 2517.321 us; speedup vs baseline: 2.2925x; 1.6571x over previous
//
#include <hip/hip_runtime.h>

#define NN 100000      // N_NODES
#define NE 1000000     // N_EDGES
#define HID 75
#define SP 80          // padded feature stride (fp32 h buffers)
#define HP 84          // LDS h-tile stride (bank-conflict pad, 21 float4s)
#define OUTF 64
#define BN_EPS 1e-5f

#define SCAN_ELEMS 1024
#define SCAN_NBLK ((NN + SCAN_ELEMS - 1) / SCAN_ELEMS)   // 98

// bf16 helpers
__device__ __forceinline__ ushort f2bf(float f) {
    unsigned u = __float_as_uint(f);
    u += 0x7FFF + ((u >> 16) & 1);          // round-to-nearest-even
    return (ushort)(u >> 16);
}
__device__ __forceinline__ float bf_lo(unsigned u) { return __uint_as_float(u << 16); }
__device__ __forceinline__ float bf_hi(unsigned u) { return __uint_as_float(u & 0xFFFF0000u); }

// ---------------- CSR build ----------------
__global__ void hist_kernel(const int* __restrict__ dst, int* __restrict__ hist, int E) {
    int e = blockIdx.x * blockDim.x + threadIdx.x;
    if (e < E) atomicAdd(&hist[dst[e]], 1);
}

__global__ void dinv_kernel(const int* __restrict__ hist, float* __restrict__ dinv, int n) {
    int i = blockIdx.x * blockDim.x + threadIdx.x;
    if (i < n) dinv[i] = rsqrtf((float)hist[i] + 1.0f);   // +1 self-loop
}

__global__ void scan_pass1(const int* __restrict__ hist, int* __restrict__ bsum) {
    __shared__ int sdata[256];
    int base = blockIdx.x * SCAN_ELEMS;
    int t = threadIdx.x;
    int s = 0;
    #pragma unroll
    for (int k = 0; k < 4; ++k) {
        int i = base + t * 4 + k;
        if (i < NN) s += hist[i];
    }
    sdata[t] = s;
    __syncthreads();
    for (int off = 128; off > 0; off >>= 1) {
        if (t < off) sdata[t] += sdata[t + off];
        __syncthreads();
    }
    if (t == 0) bsum[blockIdx.x] = sdata[0];
}

__global__ void scan_pass2(int* __restrict__ bsum, int* __restrict__ row_ptr, int nblk) {
    if (threadIdx.x == 0) {
        int acc = 0;
        for (int i = 0; i < nblk; ++i) { int v = bsum[i]; bsum[i] = acc; acc += v; }
        row_ptr[NN] = acc;
    }
}

__global__ void scan_pass3(const int* __restrict__ hist, const int* __restrict__ bsum,
                           int* __restrict__ row_ptr) {
    __shared__ int sdata[256];
    int base = blockIdx.x * SCAN_ELEMS;
    int t = threadIdx.x;
    int v[4];
    int s = 0;
    #pragma unroll
    for (int k = 0; k < 4; ++k) {
        int i = base + t * 4 + k;
        v[k] = (i < NN) ? hist[i] : 0;
        s += v[k];
    }
    sdata[t] = s;
    __syncthreads();
    for (int off = 1; off < 256; off <<= 1) {
        int x = (t >= off) ? sdata[t - off] : 0;
        __syncthreads();
        sdata[t] += x;
        __syncthreads();
    }
    int pre = bsum[blockIdx.x] + sdata[t] - s;
    #pragma unroll
    for (int k = 0; k < 4; ++k) {
        int i = base + t * 4 + k;
        if (i < NN) { row_ptr[i] = pre; pre += v[k]; }
    }
}

__global__ void csr_fill(const int* __restrict__ src, const int* __restrict__ dst,
                         const int* __restrict__ row_ptr, int* __restrict__ cnt,
                         int* __restrict__ col, int E) {
    int e = blockIdx.x * blockDim.x + threadIdx.x;
    if (e >= E) return;
    int d = dst[e];
    int slot = row_ptr[d] + atomicAdd(&cnt[d], 1);
    col[slot] = src[e];
}

// ---------------- embedding gather ----------------
__global__ void embed_kernel(const int* __restrict__ x, const float* __restrict__ emb,
                             float* __restrict__ h) {
    int t = blockIdx.x * blockDim.x + threadIdx.x;
    if (t >= NN * SP) return;
    int node = t / SP, f = t % SP;
    h[t] = (f < HID) ? emb[x[node] * HID + f] : 0.0f;
}

// ---------------- GEMM: outb[n] = bf16( dinv[n] * (BNReLU(h[n]) @ W) ) ----------------
// All k-loop operands live in LDS (no global loads in the loop -> nothing for the
// compiler to hoist into spilled registers; round-4/5 failure mode eliminated).
// BN+ReLU applied ONCE per element while staging the h tile into LDS.
template<int J, bool BNRELU>
__global__ __launch_bounds__(256, 2)
void gemm_kernel(const float* __restrict__ h, const float* __restrict__ W,
                 const float* __restrict__ ab, const float* __restrict__ dinv,
                 ushort* __restrict__ outb) {
    constexpr int CJ = (J + 3) / 4;   // 19 or 16
    constexpr int JP = CJ * 4;        // 76 or 64
    constexpr int NB = 256 / CJ;      // 13 or 16 row-groups
    constexpr int ROWS = NB * 4;      // 52 or 64 rows per block
    constexpr int OS = (J == HID) ? 80 : 64;
    __shared__ __align__(16) float Wlds[76 * JP];        // 23.1 / 19.4 KB
    __shared__ __align__(16) float Hlds[ROWS * HP];      // 17.5 / 21.5 KB
    int tl = threadIdx.x;
    int rbase0 = blockIdx.x * ROWS;
    // stage W
    for (int idx = tl; idx < 76 * JP; idx += 256) {
        int k = idx / JP, j = idx % JP;
        Wlds[idx] = (k < HID && j < J) ? W[k * J + j] : 0.0f;
    }
    // stage H tile (coalesced, each element fetched once) with fused BN+ReLU
    for (int idx = tl; idx < ROWS * (SP / 4); idx += 256) {
        int r = idx / (SP / 4), f4 = idx % (SP / 4);
        int row = rbase0 + r;
        if (row >= NN) row = NN - 1;
        float4 v = reinterpret_cast<const float4*>(h + (size_t)row * SP)[f4];
        if (BNRELU) {
            float4 a4 = reinterpret_cast<const float4*>(ab)[f4];
            float4 c4 = reinterpret_cast<const float4*>(ab + SP)[f4];
            v.x = fmaxf(fmaf(v.x, a4.x, c4.x), 0.f);
            v.y = fmaxf(fmaf(v.y, a4.y, c4.y), 0.f);
            v.z = fmaxf(fmaf(v.z, a4.z, c4.z), 0.f);
            v.w = fmaxf(fmaf(v.w, a4.w, c4.w), 0.f);
        }
        reinterpret_cast<float4*>(Hlds + r * HP)[f4] = v;
    }
    __syncthreads();
    int nn_local = tl / CJ;
    int c = tl % CJ;
    if (nn_local >= NB) return;
    int rbase = rbase0 + nn_local * 4;
    if (rbase >= NN) return;
    const float* hl0 = Hlds + (nn_local * 4 + 0) * HP;
    const float* hl1 = Hlds + (nn_local * 4 + 1) * HP;
    const float* hl2 = Hlds + (nn_local * 4 + 2) * HP;
    const float* hl3 = Hlds + (nn_local * 4 + 3) * HP;
    const float* wbase = Wlds + c * 4;
    float4 acc0 = make_float4(0.f, 0.f, 0.f, 0.f);
    float4 acc1 = make_float4(0.f, 0.f, 0.f, 0.f);
    float4 acc2 = make_float4(0.f, 0.f, 0.f, 0.f);
    float4 acc3 = make_float4(0.f, 0.f, 0.f, 0.f);
    #pragma unroll
    for (int k4 = 0; k4 < 19; ++k4) {
        const float* wr = wbase + (k4 * 4) * JP;
        float4 w0 = *reinterpret_cast<const float4*>(wr);
        float4 w1 = *reinterpret_cast<const float4*>(wr + JP);
        float4 w2 = *reinterpret_cast<const float4*>(wr + 2 * JP);
        float4 w3 = *reinterpret_cast<const float4*>(wr + 3 * JP);
        float4 x;
        x = *reinterpret_cast<const float4*>(hl0 + k4 * 4);
        acc0.x = fmaf(x.x, w0.x, acc0.x); acc0.y = fmaf(x.x, w0.y, acc0.y);
        acc0.z = fmaf(x.x, w0.z, acc0.z); acc0.w = fmaf(x.x, w0.w, acc0.w);
        acc0.x = fmaf(x.y, w1.x, acc0.x); acc0.y = fmaf(x.y, w1.y, acc0.y);
        acc0.z = fmaf(x.y, w1.z, acc0.z); acc0.w = fmaf(x.y, w1.w, acc0.w);
        acc0.x = fmaf(x.z, w2.x, acc0.x); acc0.y = fmaf(x.z, w2.y, acc0.y);
        acc0.z = fmaf(x.z, w2.z, acc0.z); acc0.w = fmaf(x.z, w2.w, acc0.w);
        acc0.x = fmaf(x.w, w3.x, acc0.x); acc0.y = fmaf(x.w, w3.y, acc0.y);
        acc0.z = fmaf(x.w, w3.z, acc0.z); acc0.w = fmaf(x.w, w3.w, acc0.w);
        x = *reinterpret_cast<const float4*>(hl1 + k4 * 4);
        acc1.x = fmaf(x.x, w0.x, acc1.x); acc1.y = fmaf(x.x, w0.y, acc1.y);
        acc1.z = fmaf(x.x, w0.z, acc1.z); acc1.w = fmaf(x.x, w0.w, acc1.w);
        acc1.x = fmaf(x.y, w1.x, acc1.x); acc1.y = fmaf(x.y, w1.y, acc1.y);
        acc1.z = fmaf(x.y, w1.z, acc1.z); acc1.w = fmaf(x.y, w1.w, acc1.w);
        acc1.x = fmaf(x.z, w2.x, acc1.x); acc1.y = fmaf(x.z, w2.y, acc1.y);
        acc1.z = fmaf(x.z, w2.z, acc1.z); acc1.w = fmaf(x.z, w2.w, acc1.w);
        acc1.x = fmaf(x.w, w3.x, acc1.x); acc1.y = fmaf(x.w, w3.y, acc1.y);
        acc1.z = fmaf(x.w, w3.z, acc1.z); acc1.w = fmaf(x.w, w3.w, acc1.w);
        x = *reinterpret_cast<const float4*>(hl2 + k4 * 4);
        acc2.x = fmaf(x.x, w0.x, acc2.x); acc2.y = fmaf(x.x, w0.y, acc2.y);
        acc2.z = fmaf(x.x, w0.z, acc2.z); acc2.w = fmaf(x.x, w0.w, acc2.w);
        acc2.x = fmaf(x.y, w1.x, acc2.x); acc2.y = fmaf(x.y, w1.y, acc2.y);
        acc2.z = fmaf(x.y, w1.z, acc2.z); acc2.w = fmaf(x.y, w1.w, acc2.w);
        acc2.x = fmaf(x.z, w2.x, acc2.x); acc2.y = fmaf(x.z, w2.y, acc2.y);
        acc2.z = fmaf(x.z, w2.z, acc2.z); acc2.w = fmaf(x.z, w2.w, acc2.w);
        acc2.x = fmaf(x.w, w3.x, acc2.x); acc2.y = fmaf(x.w, w3.y, acc2.y);
        acc2.z = fmaf(x.w, w3.z, acc2.z); acc2.w = fmaf(x.w, w3.w, acc2.w);
        x = *reinterpret_cast<const float4*>(hl3 + k4 * 4);
        acc3.x = fmaf(x.x, w0.x, acc3.x); acc3.y = fmaf(x.x, w0.y, acc3.y);
        acc3.z = fmaf(x.x, w0.z, acc3.z); acc3.w = fmaf(x.x, w0.w, acc3.w);
        acc3.x = fmaf(x.y, w1.x, acc3.x); acc3.y = fmaf(x.y, w1.y, acc3.y);
        acc3.z = fmaf(x.y, w1.z, acc3.z); acc3.w = fmaf(x.y, w1.w, acc3.w);
        acc3.x = fmaf(x.z, w2.x, acc3.x); acc3.y = fmaf(x.z, w2.y, acc3.y);
        acc3.z = fmaf(x.z, w2.z, acc3.z); acc3.w = fmaf(x.z, w2.w, acc3.w);
        acc3.x = fmaf(x.w, w3.x, acc3.x); acc3.y = fmaf(x.w, w3.y, acc3.y);
        acc3.z = fmaf(x.w, w3.z, acc3.z); acc3.w = fmaf(x.w, w3.w, acc3.w);
    }
    float d0 = dinv[rbase];
    ushort4 o;
    ushort* orow = outb + (size_t)rbase * OS;
    o.x = f2bf(acc0.x * d0); o.y = f2bf(acc0.y * d0); o.z = f2bf(acc0.z * d0); o.w = f2bf(acc0.w * d0);
    reinterpret_cast<ushort4*>(orow)[c] = o;
    if (J == HID && c == 0) reinterpret_cast<ushort4*>(orow)[19] = make_ushort4(0, 0, 0, 0);
    if (rbase + 1 < NN) {
        float d = dinv[rbase + 1];
        orow = outb + (size_t)(rbase + 1) * OS;
        o.x = f2bf(acc1.x * d); o.y = f2bf(acc1.y * d); o.z = f2bf(acc1.z * d); o.w = f2bf(acc1.w * d);
        reinterpret_cast<ushort4*>(orow)[c] = o;
        if (J == HID && c == 0) reinterpret_cast<ushort4*>(orow)[19] = make_ushort4(0, 0, 0, 0);
    }
    if (rbase + 2 < NN) {
        float d = dinv[rbase + 2];
        orow = outb + (size_t)(rbase + 2) * OS;
        o.x = f2bf(acc2.x * d); o.y = f2bf(acc2.y * d); o.z = f2bf(acc2.z * d); o.w = f2bf(acc2.w * d);
        reinterpret_cast<ushort4*>(orow)[c] = o;
        if (J == HID && c == 0) reinterpret_cast<ushort4*>(orow)[19] = make_ushort4(0, 0, 0, 0);
    }
    if (rbase + 3 < NN) {
        float d = dinv[rbase + 3];
        orow = outb + (size_t)(rbase + 3) * OS;
        o.x = f2bf(acc3.x * d); o.y = f2bf(acc3.y * d); o.z = f2bf(acc3.z * d); o.w = f2bf(acc3.w * d);
        reinterpret_cast<ushort4*>(orow)[c] = o;
        if (J == HID && c == 0) reinterpret_cast<ushort4*>(orow)[19] = make_ushort4(0, 0, 0, 0);
    }
}

// ---------------- CSR gather (bf16 uint2 loads, 4-deep MLP, no barriers) ----------------
#define ACCUM(W) \
    a0 += bf_lo(W.x); a1 += bf_hi(W.x); a2 += bf_lo(W.y); a3 += bf_hi(W.y);

// 20 lanes per row, 8B per lane. grid*block >= NN*20.
__global__ void gather75(const int* __restrict__ row_ptr, const int* __restrict__ col,
                         const uint2* __restrict__ hWb, const float* __restrict__ dinv,
                         float* __restrict__ agg) {
    int t = blockIdx.x * 256 + threadIdx.x;
    if (t >= NN * 20) return;
    int n = t / 20, c = t % 20;
    int beg = row_ptr[n], end = row_ptr[n + 1];
    uint2 v = hWb[(size_t)n * 20 + c];     // self term (pre-scaled by dinv[src])
    float a0 = bf_lo(v.x), a1 = bf_hi(v.x), a2 = bf_lo(v.y), a3 = bf_hi(v.y);
    int e = beg;
    for (; e + 3 < end; e += 4) {
        int s0 = col[e], s1 = col[e + 1], s2 = col[e + 2], s3 = col[e + 3];
        uint2 w0 = hWb[(size_t)s0 * 20 + c];
        uint2 w1 = hWb[(size_t)s1 * 20 + c];
        uint2 w2 = hWb[(size_t)s2 * 20 + c];
        uint2 w3 = hWb[(size_t)s3 * 20 + c];
        ACCUM(w0) ACCUM(w1) ACCUM(w2) ACCUM(w3)
    }
    for (; e < end; ++e) {
        uint2 w0 = hWb[(size_t)col[e] * 20 + c];
        ACCUM(w0)
    }
    float d = dinv[n];
    reinterpret_cast<float4*>(agg)[(size_t)n * 20 + c] =
        make_float4(a0 * d, a1 * d, a2 * d, a3 * d);
}

// 16 lanes per row, 8B per lane. grid*block == NN*16 exactly. Adds bias.
__global__ void gather64(const int* __restrict__ row_ptr, const int* __restrict__ col,
                         const uint2* __restrict__ hWb, const float* __restrict__ dinv,
                         const float* __restrict__ bias, float* __restrict__ out) {
    int t = blockIdx.x * 256 + threadIdx.x;
    int n = t / 16, c = t % 16;
    int beg = row_ptr[n], end = row_ptr[n + 1];
    uint2 v = hWb[(size_t)n * 16 + c];
    float a0 = bf_lo(v.x), a1 = bf_hi(v.x), a2 = bf_lo(v.y), a3 = bf_hi(v.y);
    int e = beg;
    for (; e + 3 < end; e += 4) {
        int s0 = col[e], s1 = col[e + 1], s2 = col[e + 2], s3 = col[e + 3];
        uint2 w0 = hWb[(size_t)s0 * 16 + c];
        uint2 w1 = hWb[(size_t)s1 * 16 + c];
        uint2 w2 = hWb[(size_t)s2 * 16 + c];
        uint2 w3 = hWb[(size_t)s3 * 16 + c];
        ACCUM(w0) ACCUM(w1) ACCUM(w2) ACCUM(w3)
    }
    for (; e < end; ++e) {
        uint2 w0 = hWb[(size_t)col[e] * 16 + c];
        ACCUM(w0)
    }
    float d = dinv[n];
    float4 b = *reinterpret_cast<const float4*>(bias + c * 4);
    reinterpret_cast<float4*>(out)[(size_t)n * 16 + c] =
        make_float4(fmaf(a0, d, b.x), fmaf(a1, d, b.y), fmaf(a2, d, b.z), fmaf(a3, d, b.w));
}

// ---------------- BN stats: column sum & sumsq ----------------
__global__ void stats_kernel(const float* __restrict__ agg, float* __restrict__ stats) {
    __shared__ float ssum[SP], ssq[SP];
    if (threadIdx.x < SP) { ssum[threadIdx.x] = 0.f; ssq[threadIdx.x] = 0.f; }
    __syncthreads();
    int gtid = blockIdx.x * blockDim.x + threadIdx.x;
    int T = gridDim.x * blockDim.x;          // divisible by 20
    int c = gtid % 20;
    int r = gtid / 20;
    int rstep = T / 20;
    float4 s = make_float4(0.f, 0.f, 0.f, 0.f), q = make_float4(0.f, 0.f, 0.f, 0.f);
    for (; r < NN; r += rstep) {
        float4 v = reinterpret_cast<const float4*>(agg)[r * 20 + c];
        s.x += v.x; s.y += v.y; s.z += v.z; s.w += v.w;
        q.x += v.x * v.x; q.y += v.y * v.y; q.z += v.z * v.z; q.w += v.w * v.w;
    }
    atomicAdd(&ssum[c * 4 + 0], s.x); atomicAdd(&ssum[c * 4 + 1], s.y);
    atomicAdd(&ssum[c * 4 + 2], s.z); atomicAdd(&ssum[c * 4 + 3], s.w);
    atomicAdd(&ssq[c * 4 + 0], q.x); atomicAdd(&ssq[c * 4 + 1], q.y);
    atomicAdd(&ssq[c * 4 + 2], q.z); atomicAdd(&ssq[c * 4 + 3], q.w);
    __syncthreads();
    if (threadIdx.x < SP) {
        atomicAdd(&stats[threadIdx.x], ssum[threadIdx.x]);
        atomicAdd(&stats[SP + threadIdx.x], ssq[threadIdx.x]);
    }
}

__global__ void bn_finalize(const float* __restrict__ stats, const float* __restrict__ gamma,
                            const float* __restrict__ beta, float* __restrict__ ab) {
    int f = threadIdx.x;
    if (f >= SP) return;
    float a = 0.f, cc = 0.f;
    if (f < HID) {
        float mu = stats[f] * (1.0f / NN);
        float var = stats[SP + f] * (1.0f / NN) - mu * mu;
        a = gamma[f] * rsqrtf(var + BN_EPS);
        cc = beta[f] - mu * a;
    }
    ab[f] = a;
    ab[SP + f] = cc;
}

// ---------------- host ----------------
extern "C" void kernel_launch(void* const* d_in, const int* in_sizes, int n_in,
                              void* d_out, int out_size, void* d_ws, size_t ws_size,
                              hipStream_t stream) {
    const int*   x      = (const int*)d_in[0];
    const int*   ei     = (const int*)d_in[1];
    const float* emb    = (const float*)d_in[2];
    const float* Ws     = (const float*)d_in[3];
    const float* gammas = (const float*)d_in[5];
    const float* betas  = (const float*)d_in[6];
    const float* W_mu   = (const float*)d_in[7];
    const float* b_mu   = (const float*)d_in[8];
    const float* W_ls   = (const float*)d_in[9];
    const float* b_ls   = (const float*)d_in[10];
    float* out = (float*)d_out;

    const int E = in_sizes[1] / 2;
    const int* src = ei;
    const int* dst = ei + E;

    char* ws = (char*)d_ws;
    float*  dinv    = (float*) (ws + 0);            // NN floats
    float*  stats   = (float*) (ws + 400000);       // 160 floats
    float*  ab      = (float*) (ws + 400640);       // 160 floats
    int*    hist    = (int*)   (ws + 401408);       // NN ints
    int*    row_ptr = (int*)   (ws + 801408);       // NN+1 ints
    int*    cnt     = (int*)   (ws + 1201536);      // NN ints
    int*    bsum    = (int*)   (ws + 1601536);      // SCAN_NBLK ints
    int*    col     = (int*)   (ws + 1602048);      // NE ints (4 MB)
    float*  hA      = (float*) (ws + 5602048);      // NN*SP fp32 (32 MB)
    ushort* hBb     = (ushort*)(ws + 37602048);     // NN*80 bf16 (16 MB)

    // --- CSR build ---
    hipMemsetAsync(hist, 0, NN * sizeof(int), stream);
    hist_kernel<<<(E + 255) / 256, 256, 0, stream>>>(dst, hist, E);
    dinv_kernel<<<(NN + 255) / 256, 256, 0, stream>>>(hist, dinv, NN);
    scan_pass1<<<SCAN_NBLK, 256, 0, stream>>>(hist, bsum);
    scan_pass2<<<1, 64, 0, stream>>>(bsum, row_ptr, SCAN_NBLK);
    scan_pass3<<<SCAN_NBLK, 256, 0, stream>>>(hist, bsum, row_ptr);
    hipMemsetAsync(cnt, 0, NN * sizeof(int), stream);
    csr_fill<<<(E + 255) / 256, 256, 0, stream>>>(src, dst, row_ptr, cnt, col, E);

    // --- h0 = emb[x] ---
    embed_kernel<<<(NN * SP + 255) / 256, 256, 0, stream>>>(x, emb, hA);

    // --- 4 GCN+BN+ReLU layers ---
    for (int layer = 0; layer < 4; ++layer) {
        const float* W = Ws + (size_t)layer * HID * HID;
        if (layer == 0)
            gemm_kernel<HID, false><<<(NN + 51) / 52, 256, 0, stream>>>(hA, W, ab, dinv, hBb);
        else
            gemm_kernel<HID, true><<<(NN + 51) / 52, 256, 0, stream>>>(hA, W, ab, dinv, hBb);
        gather75<<<(NN * 20 + 255) / 256, 256, 0, stream>>>(row_ptr, col, (const uint2*)hBb, dinv, hA);
        hipMemsetAsync(stats, 0, 2 * SP * sizeof(float), stream);
        stats_kernel<<<640, 256, 0, stream>>>(hA, stats);
        bn_finalize<<<1, 128, 0, stream>>>(stats, gammas + layer * HID, betas + layer * HID, ab);
    }

    // --- mu ---
    gemm_kernel<OUTF, true><<<(NN + 63) / 64, 256, 0, stream>>>(hA, W_mu, ab, dinv, hBb);
    gather64<<<(NN * 16) / 256, 256, 0, stream>>>(row_ptr, col, (const uint2*)hBb, dinv, b_mu, out);

    // --- logstd ---
    float* out2 = out + (size_t)NN * OUTF;
    gemm_kernel<OUTF, true><<<(NN + 63) / 64, 256, 0, stream>>>(hA, W_ls, ab, dinv, hBb);
    gather64<<<(NN * 16) / 256, 256, 0, stream>>>(row_ptr, col, (const uint2*)hBb, dinv, b_ls, out2);
}

// Round 7
// 704.916 us; speedup vs baseline: 8.1866x; 3.5711x over previous
//
#include <hip/hip_runtime.h>

#define NN 100000      // N_NODES
#define NE 1000000     // N_EDGES
#define HID 75
#define SP 80          // padded feature stride (fp32 h buffers)
#define OUTF 64
#define BN_EPS 1e-5f

#define SCAN_ELEMS 1024
#define SCAN_NBLK ((NN + SCAN_ELEMS - 1) / SCAN_ELEMS)   // 98

// bf16 helpers
__device__ __forceinline__ ushort f2bf(float f) {
    unsigned u = __float_as_uint(f);
    u += 0x7FFF + ((u >> 16) & 1);          // round-to-nearest-even
    return (ushort)(u >> 16);
}
__device__ __forceinline__ float bf_lo(unsigned u) { return __uint_as_float(u << 16); }
__device__ __forceinline__ float bf_hi(unsigned u) { return __uint_as_float(u & 0xFFFF0000u); }

// ---------------- CSR build ----------------
__global__ void hist_kernel(const int* __restrict__ dst, int* __restrict__ hist, int E) {
    int e = blockIdx.x * blockDim.x + threadIdx.x;
    if (e < E) atomicAdd(&hist[dst[e]], 1);
}

__global__ void dinv_kernel(const int* __restrict__ hist, float* __restrict__ dinv, int n) {
    int i = blockIdx.x * blockDim.x + threadIdx.x;
    if (i < n) dinv[i] = rsqrtf((float)hist[i] + 1.0f);   // +1 self-loop
}

__global__ void scan_pass1(const int* __restrict__ hist, int* __restrict__ bsum) {
    __shared__ int sdata[256];
    int base = blockIdx.x * SCAN_ELEMS;
    int t = threadIdx.x;
    int s = 0;
    #pragma unroll
    for (int k = 0; k < 4; ++k) {
        int i = base + t * 4 + k;
        if (i < NN) s += hist[i];
    }
    sdata[t] = s;
    __syncthreads();
    for (int off = 128; off > 0; off >>= 1) {
        if (t < off) sdata[t] += sdata[t + off];
        __syncthreads();
    }
    if (t == 0) bsum[blockIdx.x] = sdata[0];
}

__global__ void scan_pass2(int* __restrict__ bsum, int* __restrict__ row_ptr, int nblk) {
    if (threadIdx.x == 0) {
        int acc = 0;
        for (int i = 0; i < nblk; ++i) { int v = bsum[i]; bsum[i] = acc; acc += v; }
        row_ptr[NN] = acc;
    }
}

__global__ void scan_pass3(const int* __restrict__ hist, const int* __restrict__ bsum,
                           int* __restrict__ row_ptr) {
    __shared__ int sdata[256];
    int base = blockIdx.x * SCAN_ELEMS;
    int t = threadIdx.x;
    int v[4];
    int s = 0;
    #pragma unroll
    for (int k = 0; k < 4; ++k) {
        int i = base + t * 4 + k;
        v[k] = (i < NN) ? hist[i] : 0;
        s += v[k];
    }
    sdata[t] = s;
    __syncthreads();
    for (int off = 1; off < 256; off <<= 1) {
        int x = (t >= off) ? sdata[t - off] : 0;
        __syncthreads();
        sdata[t] += x;
        __syncthreads();
    }
    int pre = bsum[blockIdx.x] + sdata[t] - s;
    #pragma unroll
    for (int k = 0; k < 4; ++k) {
        int i = base + t * 4 + k;
        if (i < NN) { row_ptr[i] = pre; pre += v[k]; }
    }
}

__global__ void csr_fill(const int* __restrict__ src, const int* __restrict__ dst,
                         const int* __restrict__ row_ptr, int* __restrict__ cnt,
                         int* __restrict__ col, int E) {
    int e = blockIdx.x * blockDim.x + threadIdx.x;
    if (e >= E) return;
    int d = dst[e];
    int slot = row_ptr[d] + atomicAdd(&cnt[d], 1);
    col[slot] = src[e];
}

// ---------------- embedding gather ----------------
__global__ void embed_kernel(const int* __restrict__ x, const float* __restrict__ emb,
                             float* __restrict__ h) {
    int t = blockIdx.x * blockDim.x + threadIdx.x;
    if (t >= NN * SP) return;
    int node = t / SP, f = t % SP;
    h[t] = (f < HID) ? emb[x[node] * HID + f] : 0.0f;
}

// ---------------- GEMM: outb[n] = bf16( dinv[n] * (BNReLU(h[n]) @ W) ) ----------------
// Low-register-pressure shape (round-2 lineage, the only one that never spilled):
// CJ lanes per row-group, 2 rows/thread, W in LDS, h via broadcast float4 global
// loads, `#pragma unroll 2` so the scheduler cannot hoist loads across the whole
// k-loop and blow past the VGPR cap (rounds 4-6 failure mode).
template<int J, bool BNRELU>
__global__ __launch_bounds__(256, 4)
void gemm_kernel(const float* __restrict__ h, const float* __restrict__ W,
                 const float* __restrict__ ab, const float* __restrict__ dinv,
                 ushort* __restrict__ outb) {
    constexpr int CJ = (J + 3) / 4;   // 19 or 16
    constexpr int JP = CJ * 4;        // 76 or 64
    constexpr int NB = 256 / CJ;      // 13 or 16 row-groups
    constexpr int RPT = 2;            // rows per thread
    constexpr int ROWS = NB * RPT;    // 26 or 32 rows per block
    constexpr int OS = (J == HID) ? 80 : 64;
    __shared__ __align__(16) float Wlds[76 * JP];
    __shared__ __align__(16) float sA[SP];
    __shared__ __align__(16) float sC[SP];
    int tl = threadIdx.x;
    for (int idx = tl; idx < 76 * JP; idx += 256) {
        int k = idx / JP, j = idx % JP;
        Wlds[idx] = (k < HID && j < J) ? W[k * J + j] : 0.0f;
    }
    if (BNRELU && tl < SP) { sA[tl] = ab[tl]; sC[tl] = ab[SP + tl]; }
    __syncthreads();
    int nn_local = tl / CJ;
    int c = tl % CJ;
    if (nn_local >= NB) return;
    int r0 = blockIdx.x * ROWS + nn_local * RPT;
    if (r0 >= NN) return;
    int r1 = min(r0 + 1, NN - 1);
    const float* h0 = h + (size_t)r0 * SP;
    const float* h1 = h + (size_t)r1 * SP;
    const float* wbase = Wlds + c * 4;
    float4 acc0 = make_float4(0.f, 0.f, 0.f, 0.f);
    float4 acc1 = make_float4(0.f, 0.f, 0.f, 0.f);
    #pragma unroll 2
    for (int k4 = 0; k4 < 19; ++k4) {
        const float* wr = wbase + (k4 * 4) * JP;
        float4 w0 = *reinterpret_cast<const float4*>(wr);
        float4 w1 = *reinterpret_cast<const float4*>(wr + JP);
        float4 w2 = *reinterpret_cast<const float4*>(wr + 2 * JP);
        float4 w3 = *reinterpret_cast<const float4*>(wr + 3 * JP);
        float4 x0 = *reinterpret_cast<const float4*>(h0 + k4 * 4);
        float4 x1 = *reinterpret_cast<const float4*>(h1 + k4 * 4);
        if (BNRELU) {
            float4 a4 = *reinterpret_cast<const float4*>(sA + k4 * 4);
            float4 c4 = *reinterpret_cast<const float4*>(sC + k4 * 4);
            x0.x = fmaxf(fmaf(x0.x, a4.x, c4.x), 0.f);
            x0.y = fmaxf(fmaf(x0.y, a4.y, c4.y), 0.f);
            x0.z = fmaxf(fmaf(x0.z, a4.z, c4.z), 0.f);
            x0.w = fmaxf(fmaf(x0.w, a4.w, c4.w), 0.f);
            x1.x = fmaxf(fmaf(x1.x, a4.x, c4.x), 0.f);
            x1.y = fmaxf(fmaf(x1.y, a4.y, c4.y), 0.f);
            x1.z = fmaxf(fmaf(x1.z, a4.z, c4.z), 0.f);
            x1.w = fmaxf(fmaf(x1.w, a4.w, c4.w), 0.f);
        }
        acc0.x = fmaf(x0.x, w0.x, acc0.x); acc0.y = fmaf(x0.x, w0.y, acc0.y);
        acc0.z = fmaf(x0.x, w0.z, acc0.z); acc0.w = fmaf(x0.x, w0.w, acc0.w);
        acc0.x = fmaf(x0.y, w1.x, acc0.x); acc0.y = fmaf(x0.y, w1.y, acc0.y);
        acc0.z = fmaf(x0.y, w1.z, acc0.z); acc0.w = fmaf(x0.y, w1.w, acc0.w);
        acc0.x = fmaf(x0.z, w2.x, acc0.x); acc0.y = fmaf(x0.z, w2.y, acc0.y);
        acc0.z = fmaf(x0.z, w2.z, acc0.z); acc0.w = fmaf(x0.z, w2.w, acc0.w);
        acc0.x = fmaf(x0.w, w3.x, acc0.x); acc0.y = fmaf(x0.w, w3.y, acc0.y);
        acc0.z = fmaf(x0.w, w3.z, acc0.z); acc0.w = fmaf(x0.w, w3.w, acc0.w);
        acc1.x = fmaf(x1.x, w0.x, acc1.x); acc1.y = fmaf(x1.x, w0.y, acc1.y);
        acc1.z = fmaf(x1.x, w0.z, acc1.z); acc1.w = fmaf(x1.x, w0.w, acc1.w);
        acc1.x = fmaf(x1.y, w1.x, acc1.x); acc1.y = fmaf(x1.y, w1.y, acc1.y);
        acc1.z = fmaf(x1.y, w1.z, acc1.z); acc1.w = fmaf(x1.y, w1.w, acc1.w);
        acc1.x = fmaf(x1.z, w2.x, acc1.x); acc1.y = fmaf(x1.z, w2.y, acc1.y);
        acc1.z = fmaf(x1.z, w2.z, acc1.z); acc1.w = fmaf(x1.z, w2.w, acc1.w);
        acc1.x = fmaf(x1.w, w3.x, acc1.x); acc1.y = fmaf(x1.w, w3.y, acc1.y);
        acc1.z = fmaf(x1.w, w3.z, acc1.z); acc1.w = fmaf(x1.w, w3.w, acc1.w);
    }
    float d0 = dinv[r0];
    ushort4 o;
    ushort* orow = outb + (size_t)r0 * OS;
    o.x = f2bf(acc0.x * d0); o.y = f2bf(acc0.y * d0); o.z = f2bf(acc0.z * d0); o.w = f2bf(acc0.w * d0);
    reinterpret_cast<ushort4*>(orow)[c] = o;
    if (J == HID && c == 0) reinterpret_cast<ushort4*>(orow)[19] = make_ushort4(0, 0, 0, 0);
    if (r0 + 1 < NN) {
        float d1 = dinv[r1];
        orow = outb + (size_t)r1 * OS;
        o.x = f2bf(acc1.x * d1); o.y = f2bf(acc1.y * d1); o.z = f2bf(acc1.z * d1); o.w = f2bf(acc1.w * d1);
        reinterpret_cast<ushort4*>(orow)[c] = o;
        if (J == HID && c == 0) reinterpret_cast<ushort4*>(orow)[19] = make_ushort4(0, 0, 0, 0);
    }
}

// ---------------- CSR gather (bf16 uint2 loads, 4-deep MLP, no barriers) ----------------
#define ACCUM(W) \
    a0 += bf_lo(W.x); a1 += bf_hi(W.x); a2 += bf_lo(W.y); a3 += bf_hi(W.y);

// 20 lanes per row, 8B per lane. grid*block >= NN*20.
__global__ void gather75(const int* __restrict__ row_ptr, const int* __restrict__ col,
                         const uint2* __restrict__ hWb, const float* __restrict__ dinv,
                         float* __restrict__ agg) {
    int t = blockIdx.x * 256 + threadIdx.x;
    if (t >= NN * 20) return;
    int n = t / 20, c = t % 20;
    int beg = row_ptr[n], end = row_ptr[n + 1];
    uint2 v = hWb[(size_t)n * 20 + c];     // self term (pre-scaled by dinv[src])
    float a0 = bf_lo(v.x), a1 = bf_hi(v.x), a2 = bf_lo(v.y), a3 = bf_hi(v.y);
    int e = beg;
    for (; e + 3 < end; e += 4) {
        int s0 = col[e], s1 = col[e + 1], s2 = col[e + 2], s3 = col[e + 3];
        uint2 w0 = hWb[(size_t)s0 * 20 + c];
        uint2 w1 = hWb[(size_t)s1 * 20 + c];
        uint2 w2 = hWb[(size_t)s2 * 20 + c];
        uint2 w3 = hWb[(size_t)s3 * 20 + c];
        ACCUM(w0) ACCUM(w1) ACCUM(w2) ACCUM(w3)
    }
    for (; e < end; ++e) {
        uint2 w0 = hWb[(size_t)col[e] * 20 + c];
        ACCUM(w0)
    }
    float d = dinv[n];
    reinterpret_cast<float4*>(agg)[(size_t)n * 20 + c] =
        make_float4(a0 * d, a1 * d, a2 * d, a3 * d);
}

// 16 lanes per row, 8B per lane. grid*block == NN*16 exactly. Adds bias.
__global__ void gather64(const int* __restrict__ row_ptr, const int* __restrict__ col,
                         const uint2* __restrict__ hWb, const float* __restrict__ dinv,
                         const float* __restrict__ bias, float* __restrict__ out) {
    int t = blockIdx.x * 256 + threadIdx.x;
    int n = t / 16, c = t % 16;
    int beg = row_ptr[n], end = row_ptr[n + 1];
    uint2 v = hWb[(size_t)n * 16 + c];
    float a0 = bf_lo(v.x), a1 = bf_hi(v.x), a2 = bf_lo(v.y), a3 = bf_hi(v.y);
    int e = beg;
    for (; e + 3 < end; e += 4) {
        int s0 = col[e], s1 = col[e + 1], s2 = col[e + 2], s3 = col[e + 3];
        uint2 w0 = hWb[(size_t)s0 * 16 + c];
        uint2 w1 = hWb[(size_t)s1 * 16 + c];
        uint2 w2 = hWb[(size_t)s2 * 16 + c];
        uint2 w3 = hWb[(size_t)s3 * 16 + c];
        ACCUM(w0) ACCUM(w1) ACCUM(w2) ACCUM(w3)
    }
    for (; e < end; ++e) {
        uint2 w0 = hWb[(size_t)col[e] * 16 + c];
        ACCUM(w0)
    }
    float d = dinv[n];
    float4 b = *reinterpret_cast<const float4*>(bias + c * 4);
    reinterpret_cast<float4*>(out)[(size_t)n * 16 + c] =
        make_float4(fmaf(a0, d, b.x), fmaf(a1, d, b.y), fmaf(a2, d, b.z), fmaf(a3, d, b.w));
}

// ---------------- BN stats: column sum & sumsq ----------------
__global__ void stats_kernel(const float* __restrict__ agg, float* __restrict__ stats) {
    __shared__ float ssum[SP], ssq[SP];
    if (threadIdx.x < SP) { ssum[threadIdx.x] = 0.f; ssq[threadIdx.x] = 0.f; }
    __syncthreads();
    int gtid = blockIdx.x * blockDim.x + threadIdx.x;
    int T = gridDim.x * blockDim.x;          // divisible by 20
    int c = gtid % 20;
    int r = gtid / 20;
    int rstep = T / 20;
    float4 s = make_float4(0.f, 0.f, 0.f, 0.f), q = make_float4(0.f, 0.f, 0.f, 0.f);
    for (; r < NN; r += rstep) {
        float4 v = reinterpret_cast<const float4*>(agg)[r * 20 + c];
        s.x += v.x; s.y += v.y; s.z += v.z; s.w += v.w;
        q.x += v.x * v.x; q.y += v.y * v.y; q.z += v.z * v.z; q.w += v.w * v.w;
    }
    atomicAdd(&ssum[c * 4 + 0], s.x); atomicAdd(&ssum[c * 4 + 1], s.y);
    atomicAdd(&ssum[c * 4 + 2], s.z); atomicAdd(&ssum[c * 4 + 3], s.w);
    atomicAdd(&ssq[c * 4 + 0], q.x); atomicAdd(&ssq[c * 4 + 1], q.y);
    atomicAdd(&ssq[c * 4 + 2], q.z); atomicAdd(&ssq[c * 4 + 3], q.w);
    __syncthreads();
    if (threadIdx.x < SP) {
        atomicAdd(&stats[threadIdx.x], ssum[threadIdx.x]);
        atomicAdd(&stats[SP + threadIdx.x], ssq[threadIdx.x]);
    }
}

__global__ void bn_finalize(const float* __restrict__ stats, const float* __restrict__ gamma,
                            const float* __restrict__ beta, float* __restrict__ ab) {
    int f = threadIdx.x;
    if (f >= SP) return;
    float a = 0.f, cc = 0.f;
    if (f < HID) {
        float mu = stats[f] * (1.0f / NN);
        float var = stats[SP + f] * (1.0f / NN) - mu * mu;
        a = gamma[f] * rsqrtf(var + BN_EPS);
        cc = beta[f] - mu * a;
    }
    ab[f] = a;
    ab[SP + f] = cc;
}

// ---------------- host ----------------
extern "C" void kernel_launch(void* const* d_in, const int* in_sizes, int n_in,
                              void* d_out, int out_size, void* d_ws, size_t ws_size,
                              hipStream_t stream) {
    const int*   x      = (const int*)d_in[0];
    const int*   ei     = (const int*)d_in[1];
    const float* emb    = (const float*)d_in[2];
    const float* Ws     = (const float*)d_in[3];
    const float* gammas = (const float*)d_in[5];
    const float* betas  = (const float*)d_in[6];
    const float* W_mu   = (const float*)d_in[7];
    const float* b_mu   = (const float*)d_in[8];
    const float* W_ls   = (const float*)d_in[9];
    const float* b_ls   = (const float*)d_in[10];
    float* out = (float*)d_out;

    const int E = in_sizes[1] / 2;
    const int* src = ei;
    const int* dst = ei + E;

    char* ws = (char*)d_ws;
    float*  dinv    = (float*) (ws + 0);            // NN floats
    float*  stats   = (float*) (ws + 400000);       // 160 floats
    float*  ab      = (float*) (ws + 400640);       // 160 floats
    int*    hist    = (int*)   (ws + 401408);       // NN ints
    int*    row_ptr = (int*)   (ws + 801408);       // NN+1 ints
    int*    cnt     = (int*)   (ws + 1201536);      // NN ints
    int*    bsum    = (int*)   (ws + 1601536);      // SCAN_NBLK ints
    int*    col     = (int*)   (ws + 1602048);      // NE ints (4 MB)
    float*  hA      = (float*) (ws + 5602048);      // NN*SP fp32 (32 MB)
    ushort* hBb     = (ushort*)(ws + 37602048);     // NN*80 bf16 (16 MB)

    // --- CSR build ---
    hipMemsetAsync(hist, 0, NN * sizeof(int), stream);
    hist_kernel<<<(E + 255) / 256, 256, 0, stream>>>(dst, hist, E);
    dinv_kernel<<<(NN + 255) / 256, 256, 0, stream>>>(hist, dinv, NN);
    scan_pass1<<<SCAN_NBLK, 256, 0, stream>>>(hist, bsum);
    scan_pass2<<<1, 64, 0, stream>>>(bsum, row_ptr, SCAN_NBLK);
    scan_pass3<<<SCAN_NBLK, 256, 0, stream>>>(hist, bsum, row_ptr);
    hipMemsetAsync(cnt, 0, NN * sizeof(int), stream);
    csr_fill<<<(E + 255) / 256, 256, 0, stream>>>(src, dst, row_ptr, cnt, col, E);

    // --- h0 = emb[x] ---
    embed_kernel<<<(NN * SP + 255) / 256, 256, 0, stream>>>(x, emb, hA);

    // --- 4 GCN+BN+ReLU layers ---
    for (int layer = 0; layer < 4; ++layer) {
        const float* W = Ws + (size_t)layer * HID * HID;
        if (layer == 0)
            gemm_kernel<HID, false><<<(NN + 25) / 26, 256, 0, stream>>>(hA, W, ab, dinv, hBb);
        else
            gemm_kernel<HID, true><<<(NN + 25) / 26, 256, 0, stream>>>(hA, W, ab, dinv, hBb);
        gather75<<<(NN * 20 + 255) / 256, 256, 0, stream>>>(row_ptr, col, (const uint2*)hBb, dinv, hA);
        hipMemsetAsync(stats, 0, 2 * SP * sizeof(float), stream);
        stats_kernel<<<640, 256, 0, stream>>>(hA, stats);
        bn_finalize<<<1, 128, 0, stream>>>(stats, gammas + layer * HID, betas + layer * HID, ab);
    }

    // --- mu ---
    gemm_kernel<OUTF, true><<<(NN + 31) / 32, 256, 0, stream>>>(hA, W_mu, ab, dinv, hBb);
    gather64<<<(NN * 16) / 256, 256, 0, stream>>>(row_ptr, col, (const uint2*)hBb, dinv, b_mu, out);

    // --- logstd ---
    float* out2 = out + (size_t)NN * OUTF;
    gemm_kernel<OUTF, true><<<(NN + 31) / 32, 256, 0, stream>>>(hA, W_ls, ab, dinv, hBb);
    gather64<<<(NN * 16) / 256, 256, 0, stream>>>(row_ptr, col, (const uint2*)hBb, dinv, b_ls, out2);
}

// Round 8
// 628.698 us; speedup vs baseline: 9.1791x; 1.1212x over previous
//
#include <hip/hip_runtime.h>

#define NN 100000      // N_NODES
#define NE 1000000     // N_EDGES
#define HID 75
#define SP 80          // padded feature stride (fp32 h buffers)
#define OUTF 64
#define BN_EPS 1e-5f
#define KP 104         // LDS k-stride in bf16 (96 used; 16B-aligned, ~2-way banks)

#define SCAN_ELEMS 1024
#define SCAN_NBLK ((NN + SCAN_ELEMS - 1) / SCAN_ELEMS)   // 98

typedef short bf16x8 __attribute__((ext_vector_type(8)));
typedef float f32x4  __attribute__((ext_vector_type(4)));

// bf16 helpers
__device__ __forceinline__ ushort f2bf(float f) {
    unsigned u = __float_as_uint(f);
    u += 0x7FFF + ((u >> 16) & 1);          // round-to-nearest-even
    return (ushort)(u >> 16);
}
__device__ __forceinline__ float bf_lo(unsigned u) { return __uint_as_float(u << 16); }
__device__ __forceinline__ float bf_hi(unsigned u) { return __uint_as_float(u & 0xFFFF0000u); }

// ---------------- CSR build ----------------
__global__ void hist_kernel(const int* __restrict__ dst, int* __restrict__ hist, int E) {
    int e = blockIdx.x * blockDim.x + threadIdx.x;
    if (e < E) atomicAdd(&hist[dst[e]], 1);
}

__global__ void dinv_kernel(const int* __restrict__ hist, float* __restrict__ dinv, int n) {
    int i = blockIdx.x * blockDim.x + threadIdx.x;
    if (i < n) dinv[i] = rsqrtf((float)hist[i] + 1.0f);   // +1 self-loop
}

__global__ void scan_pass1(const int* __restrict__ hist, int* __restrict__ bsum) {
    __shared__ int sdata[256];
    int base = blockIdx.x * SCAN_ELEMS;
    int t = threadIdx.x;
    int s = 0;
    #pragma unroll
    for (int k = 0; k < 4; ++k) {
        int i = base + t * 4 + k;
        if (i < NN) s += hist[i];
    }
    sdata[t] = s;
    __syncthreads();
    for (int off = 128; off > 0; off >>= 1) {
        if (t < off) sdata[t] += sdata[t + off];
        __syncthreads();
    }
    if (t == 0) bsum[blockIdx.x] = sdata[0];
}

__global__ void scan_pass2(int* __restrict__ bsum, int* __restrict__ row_ptr, int nblk) {
    if (threadIdx.x == 0) {
        int acc = 0;
        for (int i = 0; i < nblk; ++i) { int v = bsum[i]; bsum[i] = acc; acc += v; }
        row_ptr[NN] = acc;
    }
}

__global__ void scan_pass3(const int* __restrict__ hist, const int* __restrict__ bsum,
                           int* __restrict__ row_ptr) {
    __shared__ int sdata[256];
    int base = blockIdx.x * SCAN_ELEMS;
    int t = threadIdx.x;
    int v[4];
    int s = 0;
    #pragma unroll
    for (int k = 0; k < 4; ++k) {
        int i = base + t * 4 + k;
        v[k] = (i < NN) ? hist[i] : 0;
        s += v[k];
    }
    sdata[t] = s;
    __syncthreads();
    for (int off = 1; off < 256; off <<= 1) {
        int x = (t >= off) ? sdata[t - off] : 0;
        __syncthreads();
        sdata[t] += x;
        __syncthreads();
    }
    int pre = bsum[blockIdx.x] + sdata[t] - s;
    #pragma unroll
    for (int k = 0; k < 4; ++k) {
        int i = base + t * 4 + k;
        if (i < NN) { row_ptr[i] = pre; pre += v[k]; }
    }
}

__global__ void csr_fill(const int* __restrict__ src, const int* __restrict__ dst,
                         const int* __restrict__ row_ptr, int* __restrict__ cnt,
                         int* __restrict__ col, int E) {
    int e = blockIdx.x * blockDim.x + threadIdx.x;
    if (e >= E) return;
    int d = dst[e];
    int slot = row_ptr[d] + atomicAdd(&cnt[d], 1);
    col[slot] = src[e];
}

// ---------------- embedding gather ----------------
__global__ void embed_kernel(const int* __restrict__ x, const float* __restrict__ emb,
                             float* __restrict__ h) {
    int t = blockIdx.x * blockDim.x + threadIdx.x;
    if (t >= NN * SP) return;
    int node = t / SP, f = t % SP;
    h[t] = (f < HID) ? emb[x[node] * HID + f] : 0.0f;
}

// ---------------- MFMA GEMM: outb[n] = bf16( dinv[n] * (BNReLU(h[n]) @ W) ) ----------------
// 64 rows/block, 4 waves, each wave = 16 rows x JP cols. K=75 padded to 96 (3 steps of 32).
// W staged TRANSPOSED [n][k] bf16 in LDS -> B-frags are contiguous ds_read_b128.
// H staged [64][KP] bf16 with BN+ReLU fused at staging.
// Frag maps (gfx950 16x16x32): A row=l&15,k=8*(l>>4)+i ; B col=l&15, same k;
// C/D col=l&15, row=(l>>4)*4+reg  [m89-verified].
template<int J, bool BNRELU>
__global__ __launch_bounds__(256, 2)
void gemm_mfma(const float* __restrict__ h, const float* __restrict__ W,
               const float* __restrict__ ab, const float* __restrict__ dinv,
               ushort* __restrict__ outb) {
    constexpr int NT = (J + 15) / 16;   // 5 (J=75) or 4 (J=64)
    constexpr int JP = NT * 16;         // 80 or 64
    constexpr int OS = JP;              // output stride matches gather layout
    __shared__ ushort Wl[JP * KP];
    __shared__ ushort Hl[64 * KP];
    int tl = threadIdx.x;
    int rbase = blockIdx.x * 64;
    // stage W^T (consecutive tl -> consecutive n: coalesced W reads)
    for (int idx = tl; idx < 96 * JP; idx += 256) {
        int k = idx / JP, n = idx % JP;
        float v = (k < HID && n < J) ? W[k * J + n] : 0.0f;
        Wl[n * KP + k] = f2bf(v);
    }
    // stage H tile (64 rows x 20 float4 chunks), BN+ReLU fused, bf16
    for (int idx = tl; idx < 64 * 20; idx += 256) {
        int r = idx / 20, c = idx % 20;
        int row = rbase + r; if (row >= NN) row = NN - 1;
        float4 v = reinterpret_cast<const float4*>(h + (size_t)row * SP)[c];
        if (BNRELU) {
            float4 a4 = reinterpret_cast<const float4*>(ab)[c];
            float4 c4 = reinterpret_cast<const float4*>(ab + SP)[c];
            v.x = fmaxf(fmaf(v.x, a4.x, c4.x), 0.f);
            v.y = fmaxf(fmaf(v.y, a4.y, c4.y), 0.f);
            v.z = fmaxf(fmaf(v.z, a4.z, c4.z), 0.f);
            v.w = fmaxf(fmaf(v.w, a4.w, c4.w), 0.f);
        }
        ushort4 u;
        u.x = f2bf(v.x); u.y = f2bf(v.y); u.z = f2bf(v.z); u.w = f2bf(v.w);
        *reinterpret_cast<ushort4*>(&Hl[r * KP + c * 4]) = u;
    }
    // zero k = 80..95 (pad)
    for (int idx = tl; idx < 64 * 16; idx += 256) {
        int r = idx / 16, k = 80 + (idx % 16);
        Hl[r * KP + k] = 0;
    }
    __syncthreads();
    int w = tl >> 6;            // wave 0..3 -> rows 16w..16w+15
    int l = tl & 63;
    int cq = l & 15;            // A-row / B-col within tile
    int q  = l >> 4;            // k-chunk select
    f32x4 acc[NT] = {};
    #pragma unroll
    for (int ks = 0; ks < 3; ++ks) {
        int k0 = ks * 32 + q * 8;
        bf16x8 a = *reinterpret_cast<const bf16x8*>(&Hl[(w * 16 + cq) * KP + k0]);
        #pragma unroll
        for (int t = 0; t < NT; ++t) {
            bf16x8 b = *reinterpret_cast<const bf16x8*>(&Wl[(t * 16 + cq) * KP + k0]);
            acc[t] = __builtin_amdgcn_mfma_f32_16x16x32_bf16(a, b, acc[t], 0, 0, 0);
        }
    }
    // epilogue: lane l, reg r -> row (l>>4)*4+r, col cq
    int r0 = rbase + w * 16 + q * 4;
    #pragma unroll
    for (int r = 0; r < 4; ++r) {
        int grow = r0 + r;
        if (grow < NN) {
            float d = dinv[grow];
            ushort* orow = outb + (size_t)grow * OS;
            #pragma unroll
            for (int t = 0; t < NT; ++t)
                orow[t * 16 + cq] = f2bf(acc[t][r] * d);
        }
    }
}

// ---------------- CSR gather (bf16 uint2 loads, 4-deep MLP, no barriers) ----------------
#define ACCUM(W) \
    a0 += bf_lo(W.x); a1 += bf_hi(W.x); a2 += bf_lo(W.y); a3 += bf_hi(W.y);

// 20 lanes per row, 8B per lane. grid*block >= NN*20.
__global__ void gather75(const int* __restrict__ row_ptr, const int* __restrict__ col,
                         const uint2* __restrict__ hWb, const float* __restrict__ dinv,
                         float* __restrict__ agg) {
    int t = blockIdx.x * 256 + threadIdx.x;
    if (t >= NN * 20) return;
    int n = t / 20, c = t % 20;
    int beg = row_ptr[n], end = row_ptr[n + 1];
    uint2 v = hWb[(size_t)n * 20 + c];     // self term (pre-scaled by dinv[src])
    float a0 = bf_lo(v.x), a1 = bf_hi(v.x), a2 = bf_lo(v.y), a3 = bf_hi(v.y);
    int e = beg;
    for (; e + 3 < end; e += 4) {
        int s0 = col[e], s1 = col[e + 1], s2 = col[e + 2], s3 = col[e + 3];
        uint2 w0 = hWb[(size_t)s0 * 20 + c];
        uint2 w1 = hWb[(size_t)s1 * 20 + c];
        uint2 w2 = hWb[(size_t)s2 * 20 + c];
        uint2 w3 = hWb[(size_t)s3 * 20 + c];
        ACCUM(w0) ACCUM(w1) ACCUM(w2) ACCUM(w3)
    }
    for (; e < end; ++e) {
        uint2 w0 = hWb[(size_t)col[e] * 20 + c];
        ACCUM(w0)
    }
    float d = dinv[n];
    reinterpret_cast<float4*>(agg)[(size_t)n * 20 + c] =
        make_float4(a0 * d, a1 * d, a2 * d, a3 * d);
}

// 16 lanes per row, 8B per lane. grid*block == NN*16 exactly. Adds bias.
__global__ void gather64(const int* __restrict__ row_ptr, const int* __restrict__ col,
                         const uint2* __restrict__ hWb, const float* __restrict__ dinv,
                         const float* __restrict__ bias, float* __restrict__ out) {
    int t = blockIdx.x * 256 + threadIdx.x;
    int n = t / 16, c = t % 16;
    int beg = row_ptr[n], end = row_ptr[n + 1];
    uint2 v = hWb[(size_t)n * 16 + c];
    float a0 = bf_lo(v.x), a1 = bf_hi(v.x), a2 = bf_lo(v.y), a3 = bf_hi(v.y);
    int e = beg;
    for (; e + 3 < end; e += 4) {
        int s0 = col[e], s1 = col[e + 1], s2 = col[e + 2], s3 = col[e + 3];
        uint2 w0 = hWb[(size_t)s0 * 16 + c];
        uint2 w1 = hWb[(size_t)s1 * 16 + c];
        uint2 w2 = hWb[(size_t)s2 * 16 + c];
        uint2 w3 = hWb[(size_t)s3 * 16 + c];
        ACCUM(w0) ACCUM(w1) ACCUM(w2) ACCUM(w3)
    }
    for (; e < end; ++e) {
        uint2 w0 = hWb[(size_t)col[e] * 16 + c];
        ACCUM(w0)
    }
    float d = dinv[n];
    float4 b = *reinterpret_cast<const float4*>(bias + c * 4);
    reinterpret_cast<float4*>(out)[(size_t)n * 16 + c] =
        make_float4(fmaf(a0, d, b.x), fmaf(a1, d, b.y), fmaf(a2, d, b.z), fmaf(a3, d, b.w));
}

// ---------------- BN stats: column sum & sumsq ----------------
__global__ void stats_kernel(const float* __restrict__ agg, float* __restrict__ stats) {
    __shared__ float ssum[SP], ssq[SP];
    if (threadIdx.x < SP) { ssum[threadIdx.x] = 0.f; ssq[threadIdx.x] = 0.f; }
    __syncthreads();
    int gtid = blockIdx.x * blockDim.x + threadIdx.x;
    int T = gridDim.x * blockDim.x;          // divisible by 20
    int c = gtid % 20;
    int r = gtid / 20;
    int rstep = T / 20;
    float4 s = make_float4(0.f, 0.f, 0.f, 0.f), q = make_float4(0.f, 0.f, 0.f, 0.f);
    for (; r < NN; r += rstep) {
        float4 v = reinterpret_cast<const float4*>(agg)[r * 20 + c];
        s.x += v.x; s.y += v.y; s.z += v.z; s.w += v.w;
        q.x += v.x * v.x; q.y += v.y * v.y; q.z += v.z * v.z; q.w += v.w * v.w;
    }
    atomicAdd(&ssum[c * 4 + 0], s.x); atomicAdd(&ssum[c * 4 + 1], s.y);
    atomicAdd(&ssum[c * 4 + 2], s.z); atomicAdd(&ssum[c * 4 + 3], s.w);
    atomicAdd(&ssq[c * 4 + 0], q.x); atomicAdd(&ssq[c * 4 + 1], q.y);
    atomicAdd(&ssq[c * 4 + 2], q.z); atomicAdd(&ssq[c * 4 + 3], q.w);
    __syncthreads();
    if (threadIdx.x < SP) {
        atomicAdd(&stats[threadIdx.x], ssum[threadIdx.x]);
        atomicAdd(&stats[SP + threadIdx.x], ssq[threadIdx.x]);
    }
}

__global__ void bn_finalize(const float* __restrict__ stats, const float* __restrict__ gamma,
                            const float* __restrict__ beta, float* __restrict__ ab) {
    int f = threadIdx.x;
    if (f >= SP) return;
    float a = 0.f, cc = 0.f;
    if (f < HID) {
        float mu = stats[f] * (1.0f / NN);
        float var = stats[SP + f] * (1.0f / NN) - mu * mu;
        a = gamma[f] * rsqrtf(var + BN_EPS);
        cc = beta[f] - mu * a;
    }
    ab[f] = a;
    ab[SP + f] = cc;
}

// ---------------- host ----------------
extern "C" void kernel_launch(void* const* d_in, const int* in_sizes, int n_in,
                              void* d_out, int out_size, void* d_ws, size_t ws_size,
                              hipStream_t stream) {
    const int*   x      = (const int*)d_in[0];
    const int*   ei     = (const int*)d_in[1];
    const float* emb    = (const float*)d_in[2];
    const float* Ws     = (const float*)d_in[3];
    const float* gammas = (const float*)d_in[5];
    const float* betas  = (const float*)d_in[6];
    const float* W_mu   = (const float*)d_in[7];
    const float* b_mu   = (const float*)d_in[8];
    const float* W_ls   = (const float*)d_in[9];
    const float* b_ls   = (const float*)d_in[10];
    float* out = (float*)d_out;

    const int E = in_sizes[1] / 2;
    const int* src = ei;
    const int* dst = ei + E;

    char* ws = (char*)d_ws;
    float*  dinv    = (float*) (ws + 0);            // NN floats
    float*  stats   = (float*) (ws + 400000);       // 160 floats
    float*  ab      = (float*) (ws + 400640);       // 160 floats
    int*    hist    = (int*)   (ws + 401408);       // NN ints
    int*    row_ptr = (int*)   (ws + 801408);       // NN+1 ints
    int*    cnt     = (int*)   (ws + 1201536);      // NN ints
    int*    bsum    = (int*)   (ws + 1601536);      // SCAN_NBLK ints
    int*    col     = (int*)   (ws + 1602048);      // NE ints (4 MB)
    float*  hA      = (float*) (ws + 5602048);      // NN*SP fp32 (32 MB)
    ushort* hBb     = (ushort*)(ws + 37602048);     // NN*80 bf16 (16 MB)

    // --- CSR build ---
    hipMemsetAsync(hist, 0, NN * sizeof(int), stream);
    hist_kernel<<<(E + 255) / 256, 256, 0, stream>>>(dst, hist, E);
    dinv_kernel<<<(NN + 255) / 256, 256, 0, stream>>>(hist, dinv, NN);
    scan_pass1<<<SCAN_NBLK, 256, 0, stream>>>(hist, bsum);
    scan_pass2<<<1, 64, 0, stream>>>(bsum, row_ptr, SCAN_NBLK);
    scan_pass3<<<SCAN_NBLK, 256, 0, stream>>>(hist, bsum, row_ptr);
    hipMemsetAsync(cnt, 0, NN * sizeof(int), stream);
    csr_fill<<<(E + 255) / 256, 256, 0, stream>>>(src, dst, row_ptr, cnt, col, E);

    // --- h0 = emb[x] ---
    embed_kernel<<<(NN * SP + 255) / 256, 256, 0, stream>>>(x, emb, hA);

    // --- 4 GCN+BN+ReLU layers ---
    for (int layer = 0; layer < 4; ++layer) {
        const float* W = Ws + (size_t)layer * HID * HID;
        if (layer == 0)
            gemm_mfma<HID, false><<<(NN + 63) / 64, 256, 0, stream>>>(hA, W, ab, dinv, hBb);
        else
            gemm_mfma<HID, true><<<(NN + 63) / 64, 256, 0, stream>>>(hA, W, ab, dinv, hBb);
        gather75<<<(NN * 20 + 255) / 256, 256, 0, stream>>>(row_ptr, col, (const uint2*)hBb, dinv, hA);
        hipMemsetAsync(stats, 0, 2 * SP * sizeof(float), stream);
        stats_kernel<<<640, 256, 0, stream>>>(hA, stats);
        bn_finalize<<<1, 128, 0, stream>>>(stats, gammas + layer * HID, betas + layer * HID, ab);
    }

    // --- mu ---
    gemm_mfma<OUTF, true><<<(NN + 63) / 64, 256, 0, stream>>>(hA, W_mu, ab, dinv, hBb);
    gather64<<<(NN * 16) / 256, 256, 0, stream>>>(row_ptr, col, (const uint2*)hBb, dinv, b_mu, out);

    // --- logstd ---
    float* out2 = out + (size_t)NN * OUTF;
    gemm_mfma<OUTF, true><<<(NN + 63) / 64, 256, 0, stream>>>(hA, W_ls, ab, dinv, hBb);
    gather64<<<(NN * 16) / 256, 256, 0, stream>>>(row_ptr, col, (const uint2*)hBb, dinv, b_ls, out2);
}